// Round 1
// baseline (764.837 us; speedup 1.0000x reference)
//
#include <hip/hip_runtime.h>
#include <hip/hip_bf16.h>
#include <math.h>

// Problem constants (from setup_inputs)
#define NPTS   32768
#define HIMG   192
#define WIMG   640

// Workspace float offsets
#define CONV_OFF0 0
#define CONV_OFF1 983040
#define CONV_OFF2 1228800
#define CONV_OFF3 1290240
#define F_Y0I   1305600   // int[4][192]
#define F_WY    1306368   // float[4][192]
#define F_X0I   1307136   // int[4][640]
#define F_WX    1309696   // float[4][640]
#define F_RY    1312256   // float[4][48]
#define F_RX    1312448   // float[4][160]
#define F_POOLED 1313088  // float[2][256]
#define F_LWS   1313600   // float[2][4]  (1+lw)
#define F_GSUM  1313608   // float[256]
#define F_PTSUM 1313864   // float[4]
#define F_GATES 1313868   // float[2][128] (1+g_pt, 1+g_img)
#define F_END   1314124

__device__ __forceinline__ float sigm(float z) { return 1.f / (1.f + expf(-z)); }

__device__ __forceinline__ void fma4(float4& a, float s, const float4& w) {
    a.x += s * w.x; a.y += s * w.y; a.z += s * w.z; a.w += s * w.w;
}

// ---------------- K0: zero accumulators (and whole small ws region) ----------
__global__ __launch_bounds__(256) void k_zero(float* __restrict__ ws) {
    size_t i = (size_t)blockIdx.x * 256 + threadIdx.x;
    size_t stride = (size_t)gridDim.x * 256;
    for (; i < (size_t)F_END; i += stride) ws[i] = 0.f;
}

// ---------------- K0b: bilinear tables (align-corners) -----------------------
__global__ void k_tables(float* __restrict__ ws) {
    int t = threadIdx.x;
    int*   y0i = (int*)(ws + F_Y0I);
    float* wy  = ws + F_WY;
    int*   x0i = (int*)(ws + F_X0I);
    float* wx  = ws + F_WX;
    float* Ry  = ws + F_RY;
    float* Rx  = ws + F_RX;
    for (int idx = t; idx < 4 * 192; idx += 256) {
        int l = idx / 192, Y = idx % 192, h = 48 >> l;
        float step = (float)(h - 1) / 191.0f;
        float ys = step * (float)Y;
        int y0 = (int)floorf(ys);
        y0i[idx] = y0; wy[idx] = ys - (float)y0;
    }
    for (int idx = t; idx < 4 * 640; idx += 256) {
        int l = idx / 640, X = idx % 640, w = 160 >> l;
        float step = (float)(w - 1) / 639.0f;
        float xs = step * (float)X;
        int x0 = (int)floorf(xs);
        x0i[idx] = x0; wx[idx] = xs - (float)x0;
    }
    for (int idx = t; idx < 4 * 48; idx += 256) {
        int l = idx / 48, hh = idx % 48, h = 48 >> l;
        float r = 0.f;
        if (hh < h) {
            float step = (float)(h - 1) / 191.0f;
            for (int Y = 0; Y < 192; ++Y) {
                float ys = step * (float)Y;
                int y0 = (int)floorf(ys);
                float f = ys - (float)y0;
                int y1 = min(y0 + 1, h - 1);
                if (y0 == hh) r += 1.f - f;
                if (y1 == hh) r += f;
            }
        }
        Ry[idx] = r;
    }
    for (int idx = t; idx < 4 * 160; idx += 256) {
        int l = idx / 160, xx = idx % 160, w = 160 >> l;
        float r = 0.f;
        if (xx < w) {
            float step = (float)(w - 1) / 639.0f;
            for (int X = 0; X < 640; ++X) {
                float xs = step * (float)X;
                int x0 = (int)floorf(xs);
                float f = xs - (float)x0;
                int x1 = min(x0 + 1, w - 1);
                if (x0 == xx) r += 1.f - f;
                if (x1 == xx) r += f;
            }
        }
        Rx[idx] = r;
    }
}

// ---------------- K1: direct 3x3 conv (fp32), ci split 4-way, atomic accum ---
// block: 256 thr = 32 spatial (8x4, each 2x2 px) x 8 cm-groups (8 cm each)
// output layout: channels-last [b][h][w][64] in ws
__global__ __launch_bounds__(256) void k_conv(
    const float* __restrict__ in,   // (B,256,h,w)
    const float* __restrict__ wts,  // (64,256,3,3) for this level
    float* __restrict__ out,        // ws + conv_off, (B,h,w,64)
    int h, int w)
{
    __shared__ float s_in[8][10][18];
    __shared__ float s_wt[8][9][64];
    int t = threadIdx.x;
    int cmg = t >> 5, sp = t & 31, spx = sp & 7, spy = sp >> 3;
    int b = blockIdx.z >> 2, split = blockIdx.z & 3;
    int gx0 = blockIdx.x * 16 - 1, gy0 = blockIdx.y * 8 - 1;

    float acc[2][2][8];
#pragma unroll
    for (int i = 0; i < 2; ++i)
#pragma unroll
        for (int j = 0; j < 2; ++j)
#pragma unroll
            for (int k = 0; k < 8; ++k) acc[i][j][k] = 0.f;

    for (int sub = 0; sub < 8; ++sub) {
        int ci0 = split * 64 + sub * 8;
        // stage input tile (8 ci x 10 x 18) with zero halo
#pragma unroll
        for (int k = 0; k < 6; ++k) {
            int idx = t + k * 256;
            if (idx < 1440) {
                int ciL = idx / 180, rem = idx % 180, yy = rem / 18, xx = rem % 18;
                int gy = gy0 + yy, gx = gx0 + xx;
                float v = 0.f;
                if (gy >= 0 && gy < h && gx >= 0 && gx < w)
                    v = in[(((size_t)b * 256 + ci0 + ciL) * h + gy) * w + gx];
                s_in[ciL][yy][xx] = v;
            }
        }
        // stage weights (8 ci x 9 taps x 64 cm)
#pragma unroll
        for (int k = 0; k < 18; ++k) {
            int idx = t + k * 256;
            int ciL = idx / 576, rem = idx % 576, tap = rem / 64, cm = rem % 64;
            s_wt[ciL][tap][cm] = wts[(size_t)(cm * 256 + ci0 + ciL) * 9 + tap];
        }
        __syncthreads();
#pragma unroll
        for (int ciL = 0; ciL < 8; ++ciL) {
            float iv[4][4];
#pragma unroll
            for (int r = 0; r < 4; ++r) {
                float2 a = *(const float2*)&s_in[ciL][2 * spy + r][2 * spx];
                float2 c = *(const float2*)&s_in[ciL][2 * spy + r][2 * spx + 2];
                iv[r][0] = a.x; iv[r][1] = a.y; iv[r][2] = c.x; iv[r][3] = c.y;
            }
#pragma unroll
            for (int ky = 0; ky < 3; ++ky)
#pragma unroll
                for (int kx = 0; kx < 3; ++kx) {
                    float4 w0 = *(const float4*)&s_wt[ciL][ky * 3 + kx][cmg * 8];
                    float4 w1 = *(const float4*)&s_wt[ciL][ky * 3 + kx][cmg * 8 + 4];
#pragma unroll
                    for (int i = 0; i < 2; ++i)
#pragma unroll
                        for (int j = 0; j < 2; ++j) {
                            float x = iv[i + ky][j + kx];
                            acc[i][j][0] += x * w0.x; acc[i][j][1] += x * w0.y;
                            acc[i][j][2] += x * w0.z; acc[i][j][3] += x * w0.w;
                            acc[i][j][4] += x * w1.x; acc[i][j][5] += x * w1.y;
                            acc[i][j][6] += x * w1.z; acc[i][j][7] += x * w1.w;
                        }
                }
        }
        __syncthreads();
    }
#pragma unroll
    for (int i = 0; i < 2; ++i)
#pragma unroll
        for (int j = 0; j < 2; ++j) {
            int oy = blockIdx.y * 8 + 2 * spy + i;
            int ox = blockIdx.x * 16 + 2 * spx + j;
            if (oy < h && ox < w) {
                float* dst = out + (((size_t)b * h + oy) * w + ox) * 64 + cmg * 8;
#pragma unroll
                for (int k = 0; k < 8; ++k) atomicAdd(dst + k, acc[i][j][k]);
            }
        }
}

// ---------------- K2: finalize (bias,scale,offset,relu) + weighted pool ------
__global__ __launch_bounds__(256) void k_finalize(
    float* __restrict__ ws,
    const float* __restrict__ lat_b, const float* __restrict__ lat_s,
    const float* __restrict__ lat_o,
    int l, int h, int w, int conv_off)
{
    __shared__ float s_red[256];
    int t = threadIdx.x;
    int b = blockIdx.y;
    int r0 = blockIdx.x * 2;
    int nrows = min(2, h - r0);
    int cm = t & 63;
    float bb = lat_b[l * 64 + cm], sc = lat_s[l * 64 + cm], of = lat_o[l * 64 + cm];
    const float* Ry = ws + F_RY + l * 48;
    const float* Rx = ws + F_RX + l * 160;
    float* conv = ws + conv_off;
    float wsum = 0.f;
    int npix = nrows * w;
    for (int p = (t >> 6); p < npix; p += 4) {
        int row = r0 + p / w, x = p % w;
        size_t idx = (((size_t)b * h + row) * w + x) * 64 + cm;
        float v = fmaxf((conv[idx] + bb) * sc + of, 0.f);
        conv[idx] = v;
        wsum += v * Ry[row] * Rx[x];
    }
    s_red[t] = wsum;
    __syncthreads();
    if (t < 64) {
        float s = s_red[t] + s_red[t + 64] + s_red[t + 128] + s_red[t + 192];
        atomicAdd(ws + F_POOLED + (size_t)b * 256 + l * 64 + t, s);
    }
}

// ---------------- K2b: level-attention gates lw -------------------------------
__global__ void k_lw(float* __restrict__ ws,
                     const float* __restrict__ la_w1, const float* __restrict__ la_b1,
                     const float* __restrict__ la_w2, const float* __restrict__ la_b2)
{
    __shared__ float s_hid[2][32];
    int t = threadIdx.x;
    const float invHW = 1.f / (192.f * 640.f);
    if (t < 64) {
        int bb = t >> 5, j = t & 31;
        float acc = la_b1[j];
        const float* P = ws + F_POOLED + bb * 256;
        for (int c = 0; c < 256; ++c) acc += P[c] * invHW * la_w1[j * 256 + c];
        s_hid[bb][j] = fmaxf(acc, 0.f);
    }
    __syncthreads();
    if (t < 8) {
        int bb = t >> 2, l = t & 3;
        float z = la_b2[l];
        for (int j = 0; j < 32; ++j) z += s_hid[bb][j] * la_w2[l * 32 + j];
        ws[F_LWS + bb * 4 + l] = 1.f + sigm(z);
    }
}

// ---------------- K3: project + gather + (256->128) transform ----------------
// 32 points per block; img_pre written to d_out; gsum/ptsum accumulated.
__global__ __launch_bounds__(256) void k_gather(
    float* __restrict__ ws,
    const float* __restrict__ points, const float* __restrict__ calib,
    const float* __restrict__ imgt_w, const float* __restrict__ imgt_b,
    const float* __restrict__ imgt_s, const float* __restrict__ imgt_o,
    float* __restrict__ dout)
{
    __shared__ float s_g[32][260];
    __shared__ float s_w[32][132];
    __shared__ int s_vi[32], s_ui[32], s_on[32], s_bi[32];
    int t = threadIdx.x;
    int n0 = blockIdx.x * 32;

    if (t < 32) {
        int n = n0 + t;
        int b = n >> 14;
        const float* P = points + (size_t)n * 5;
        float x = P[1], y = P[2], z = P[3], it = P[4];
        const float* C = calib + b * 12;
        float pu = C[0] * x + C[1] * y + C[2] * z + C[3];
        float pv = C[4] * x + C[5] * y + C[6] * z + C[7];
        float pz = C[8] * x + C[9] * y + C[10] * z + C[11];
        float zs = fmaxf(pz, 1e-5f);
        float u = pu / zs, v = pv / zs;
        int on = (u >= 0.f) && (u < 640.f) && (v >= 0.f) && (v < 192.f) && (pz > 1e-5f);
        s_on[t] = on; s_bi[t] = b;
        s_ui[t] = min(max((int)u, 0), 639);
        s_vi[t] = min(max((int)v, 0), 191);
#pragma unroll
        for (int m = 16; m >= 1; m >>= 1) {
            x += __shfl_xor(x, m); y += __shfl_xor(y, m);
            z += __shfl_xor(z, m); it += __shfl_xor(it, m);
        }
        if (t == 0) {
            atomicAdd(ws + F_PTSUM + 0, x);
            atomicAdd(ws + F_PTSUM + 1, y);
            atomicAdd(ws + F_PTSUM + 2, z);
            atomicAdd(ws + F_PTSUM + 3, it);
        }
    }
    __syncthreads();

    // phase 1: bilinear gather of 256 ch per point into LDS (scaled by 1+lw)
    {
        int p = t >> 3, sub = t & 7;
        int l = sub >> 1, cmh = (sub & 1) * 32;
        if (!s_on[p]) {
#pragma unroll
            for (int k = 0; k < 32; k += 4)
                *(float4*)&s_g[p][l * 64 + cmh + k] = make_float4(0.f, 0.f, 0.f, 0.f);
        } else {
            int b = s_bi[p], vi = s_vi[p], ui = s_ui[p];
            int h = 48 >> l, w = 160 >> l;
            const int* y0i = (const int*)(ws + F_Y0I);
            const int* x0i = (const int*)(ws + F_X0I);
            int y0 = y0i[l * 192 + vi]; float fy = ws[F_WY + l * 192 + vi];
            int x0 = x0i[l * 640 + ui]; float fx = ws[F_WX + l * 640 + ui];
            int y1 = min(y0 + 1, h - 1), x1 = min(x0 + 1, w - 1);
            int coff = (l == 0) ? CONV_OFF0 : (l == 1) ? CONV_OFF1 : (l == 2) ? CONV_OFF2 : CONV_OFF3;
            const float* base = ws + coff;
            const float* A00 = base + (((size_t)b * h + y0) * w + x0) * 64;
            const float* A01 = base + (((size_t)b * h + y0) * w + x1) * 64;
            const float* A10 = base + (((size_t)b * h + y1) * w + x0) * 64;
            const float* A11 = base + (((size_t)b * h + y1) * w + x1) * 64;
            float w00 = (1.f - fy) * (1.f - fx), w01 = (1.f - fy) * fx;
            float w10 = fy * (1.f - fx), w11 = fy * fx;
            float sc = ws[F_LWS + b * 4 + l];
#pragma unroll
            for (int k = 0; k < 32; k += 4) {
                float4 v00 = *(const float4*)(A00 + cmh + k);
                float4 v01 = *(const float4*)(A01 + cmh + k);
                float4 v10 = *(const float4*)(A10 + cmh + k);
                float4 v11 = *(const float4*)(A11 + cmh + k);
                float4 r;
                r.x = (w00 * v00.x + w01 * v01.x + w10 * v10.x + w11 * v11.x) * sc;
                r.y = (w00 * v00.y + w01 * v01.y + w10 * v10.y + w11 * v11.y) * sc;
                r.z = (w00 * v00.z + w01 * v01.z + w10 * v10.z + w11 * v11.z) * sc;
                r.w = (w00 * v00.w + w01 * v01.w + w10 * v10.w + w11 * v11.w) * sc;
                *(float4*)&s_g[p][l * 64 + cmh + k] = r;
            }
        }
    }
    __syncthreads();

    // gsum accumulation (column sums over 32 points)
    {
        float s = 0.f;
#pragma unroll 8
        for (int p = 0; p < 32; ++p) s += s_g[p][t];
        atomicAdd(ws + F_GSUM + t, s);
    }

    // phase 2: img_pre = (g @ imgt_w^T + b)*s + o ; register tile 4pts x 4o
    int og = t & 31, pg = t >> 5;
    int o4 = og * 4, p4 = pg * 4;
    float4 acc[4];
#pragma unroll
    for (int i = 0; i < 4; ++i) acc[i] = make_float4(0.f, 0.f, 0.f, 0.f);

    for (int ch = 0; ch < 8; ++ch) {
        int c0 = ch * 32;
        __syncthreads();
#pragma unroll
        for (int k = 0; k < 16; ++k) {
            int idx = t + k * 256;
            int o = idx >> 5, cl = idx & 31;
            s_w[cl][o] = imgt_w[(size_t)o * 256 + c0 + cl];
        }
        __syncthreads();
#pragma unroll
        for (int cq = 0; cq < 8; ++cq) {
            int c = c0 + cq * 4, cl = cq * 4;
            float4 w0 = *(const float4*)&s_w[cl + 0][o4];
            float4 w1 = *(const float4*)&s_w[cl + 1][o4];
            float4 w2 = *(const float4*)&s_w[cl + 2][o4];
            float4 w3 = *(const float4*)&s_w[cl + 3][o4];
#pragma unroll
            for (int i = 0; i < 4; ++i) {
                float4 g = *(const float4*)&s_g[p4 + i][c];
                fma4(acc[i], g.x, w0);
                fma4(acc[i], g.y, w1);
                fma4(acc[i], g.z, w2);
                fma4(acc[i], g.w, w3);
            }
        }
    }
    float4 vb = *(const float4*)(imgt_b + o4);
    float4 vs = *(const float4*)(imgt_s + o4);
    float4 vo = *(const float4*)(imgt_o + o4);
#pragma unroll
    for (int i = 0; i < 4; ++i) {
        int n = n0 + p4 + i;
        float4 r;
        r.x = (acc[i].x + vb.x) * vs.x + vo.x;
        r.y = (acc[i].y + vb.y) * vs.y + vo.y;
        r.z = (acc[i].z + vb.z) * vs.z + vo.z;
        r.w = (acc[i].w + vb.w) * vs.w + vo.w;
        *(float4*)&dout[(size_t)n * 128 + o4] = r;
    }
}

// ---------------- K4: SE gates from pooled cross vector ----------------------
__global__ void k_se(float* __restrict__ ws,
                     const float* __restrict__ imgt_w, const float* __restrict__ imgt_b,
                     const float* __restrict__ imgt_s, const float* __restrict__ imgt_o,
                     const float* __restrict__ pts_w, const float* __restrict__ pts_b,
                     const float* __restrict__ pts_s, const float* __restrict__ pts_o,
                     const float* __restrict__ w1p, const float* __restrict__ w2p,
                     const float* __restrict__ w1i, const float* __restrict__ w2i)
{
    __shared__ float s_cross[256];
    __shared__ float s_hp[128], s_hi[128];
    int t = threadIdx.x;  // 128 threads
    const float invN = 1.f / (float)NPTS;
    float a = 0.f;
    for (int c = 0; c < 256; ++c) a += ws[F_GSUM + c] * imgt_w[(size_t)t * 256 + c];
    s_cross[t] = (a * invN + imgt_b[t]) * imgt_s[t] + imgt_o[t];
    float pp = 0.f;
    for (int k = 0; k < 4; ++k) pp += ws[F_PTSUM + k] * invN * pts_w[t * 4 + k];
    s_cross[128 + t] = (pp + pts_b[t]) * pts_s[t] + pts_o[t];
    __syncthreads();
    float h1 = 0.f, h2 = 0.f;
    for (int c = 0; c < 256; ++c) {
        float cv = s_cross[c];
        h1 += cv * w1p[(size_t)t * 256 + c];
        h2 += cv * w1i[(size_t)t * 256 + c];
    }
    s_hp[t] = fmaxf(h1, 0.f); s_hi[t] = fmaxf(h2, 0.f);
    __syncthreads();
    float g1 = 0.f, g2 = 0.f;
    for (int hh = 0; hh < 128; ++hh) {
        g1 += s_hp[hh] * w2p[(size_t)t * 128 + hh];
        g2 += s_hi[hh] * w2i[(size_t)t * 128 + hh];
    }
    ws[F_GATES + t]       = 1.f + sigm(g1);
    ws[F_GATES + 128 + t] = 1.f + sigm(g2);
}

// ---------------- K5: fuse (in-place on d_out) --------------------------------
__global__ __launch_bounds__(256) void k_fuse(
    float* __restrict__ dout, const float* __restrict__ ws,
    const float* __restrict__ points,
    const float* __restrict__ pts_w, const float* __restrict__ pts_b,
    const float* __restrict__ pts_s, const float* __restrict__ pts_o)
{
    int gid = blockIdx.x * 256 + threadIdx.x;
    int n = gid >> 5, oq = (gid & 31) * 4;
    const float* P = points + (size_t)n * 5;
    float x = P[1], y = P[2], z = P[3], it = P[4];
    float4 img = *(float4*)&dout[(size_t)n * 128 + oq];
    float4 g1 = *(const float4*)(ws + F_GATES + oq);
    float4 g2 = *(const float4*)(ws + F_GATES + 128 + oq);
    float r[4], im[4] = {img.x, img.y, img.z, img.w};
    float ga[4] = {g1.x, g1.y, g1.z, g1.w};
    float gb[4] = {g2.x, g2.y, g2.z, g2.w};
#pragma unroll
    for (int j = 0; j < 4; ++j) {
        int o = oq + j;
        float4 wr = *(const float4*)(pts_w + o * 4);
        float pp = x * wr.x + y * wr.y + z * wr.z + it * wr.w;
        pp = (pp + pts_b[o]) * pts_s[o] + pts_o[o];
        r[j] = fmaxf(im[j] * ga[j] + pp * gb[j], 0.f);
    }
    float4 out4 = make_float4(r[0], r[1], r[2], r[3]);
    *(float4*)&dout[(size_t)n * 128 + oq] = out4;
}

// ---------------- launch ------------------------------------------------------
extern "C" void kernel_launch(void* const* d_in, const int* in_sizes, int n_in,
                              void* d_out, int out_size, void* d_ws, size_t ws_size,
                              hipStream_t stream)
{
    const float* fpn[4] = {(const float*)d_in[0], (const float*)d_in[1],
                           (const float*)d_in[2], (const float*)d_in[3]};
    const float* points = (const float*)d_in[4];
    const float* calib  = (const float*)d_in[5];
    const float* lat_w  = (const float*)d_in[6];
    const float* lat_b  = (const float*)d_in[7];
    const float* lat_s  = (const float*)d_in[8];
    const float* lat_o  = (const float*)d_in[9];
    const float* pts_w  = (const float*)d_in[10];
    const float* pts_b  = (const float*)d_in[11];
    const float* pts_s  = (const float*)d_in[12];
    const float* pts_o  = (const float*)d_in[13];
    const float* imgt_w = (const float*)d_in[14];
    const float* imgt_b = (const float*)d_in[15];
    const float* imgt_s = (const float*)d_in[16];
    const float* imgt_o = (const float*)d_in[17];
    const float* la_w1  = (const float*)d_in[18];
    const float* la_b1  = (const float*)d_in[19];
    const float* la_w2  = (const float*)d_in[20];
    const float* la_b2  = (const float*)d_in[21];
    const float* se_pt_w1  = (const float*)d_in[22];
    const float* se_pt_w2  = (const float*)d_in[23];
    const float* se_img_w1 = (const float*)d_in[24];
    const float* se_img_w2 = (const float*)d_in[25];

    float* ws = (float*)d_ws;
    float* dout = (float*)d_out;

    k_zero<<<1024, 256, 0, stream>>>(ws);
    k_tables<<<1, 256, 0, stream>>>(ws);

    const int hs[4]  = {48, 24, 12, 6};
    const int wws[4] = {160, 80, 40, 20};
    const int coff[4] = {CONV_OFF0, CONV_OFF1, CONV_OFF2, CONV_OFF3};
    for (int l = 0; l < 4; ++l) {
        dim3 grid((wws[l] + 15) / 16, (hs[l] + 7) / 8, 2 * 4);
        k_conv<<<grid, 256, 0, stream>>>(fpn[l], lat_w + (size_t)l * 64 * 256 * 9,
                                         ws + coff[l], hs[l], wws[l]);
    }
    for (int l = 0; l < 4; ++l) {
        dim3 grid((hs[l] + 1) / 2, 2);
        k_finalize<<<grid, 256, 0, stream>>>(ws, lat_b, lat_s, lat_o, l, hs[l], wws[l], coff[l]);
    }
    k_lw<<<1, 64, 0, stream>>>(ws, la_w1, la_b1, la_w2, la_b2);
    k_gather<<<NPTS / 32, 256, 0, stream>>>(ws, points, calib, imgt_w, imgt_b,
                                            imgt_s, imgt_o, dout);
    k_se<<<1, 128, 0, stream>>>(ws, imgt_w, imgt_b, imgt_s, imgt_o,
                                pts_w, pts_b, pts_s, pts_o,
                                se_pt_w1, se_pt_w2, se_img_w1, se_img_w2);
    k_fuse<<<NPTS * 32 / 256, 256, 0, stream>>>(dout, ws, points,
                                                pts_w, pts_b, pts_s, pts_o);
}

// Round 2
// 286.623 us; speedup vs baseline: 2.6684x; 2.6684x over previous
//
#include <hip/hip_runtime.h>
#include <hip/hip_bf16.h>
#include <math.h>

#define NPTS   32768

// Workspace float offsets
#define CONV_OFF0 0
#define CONV_OFF1 983040
#define CONV_OFF2 1228800
#define CONV_OFF3 1290240
#define F_Y0I   1305600   // int[4][192]
#define F_WY    1306368   // float[4][192]
#define F_X0I   1307136   // int[4][640]
#define F_WX    1309696   // float[4][640]
#define F_RY    1312256   // float[4][48]
#define F_RX    1312448   // float[4][160]
#define F_POOLED 1313088  // float[2][256]
#define F_LWS   1313600   // float[2][4]  (1+lw)
#define F_GSUM  1313608   // float[256]
#define F_PTSUM 1313864   // float[4]
#define F_GATES 1313868   // float[2][128]
#define F_END   1314124
#define F_INBF  1314176   // bf16 channels-last inputs: 5,222,400 bf16 ele
#define INBF_ELE 5222400
#define F_WPACK (F_INBF + INBF_ELE/2)   // 3,925,376; bf16 packed weights 589,824 ele
// total ~16.9 MB

typedef short bf16x8 __attribute__((ext_vector_type(8)));
typedef float f32x4  __attribute__((ext_vector_type(4)));

__device__ __forceinline__ float sigm(float z) { return 1.f / (1.f + expf(-z)); }

__device__ __forceinline__ void fma4(float4& a, float s, const float4& w) {
    a.x += s * w.x; a.y += s * w.y; a.z += s * w.z; a.w += s * w.w;
}

// ---------------- K0: zero small accumulator region --------------------------
__global__ void k_zero_small(float* __restrict__ ws) {
    for (int i = threadIdx.x; i < (F_END - F_POOLED); i += 256) ws[F_POOLED + i] = 0.f;
}

// ---------------- K0b: bilinear tables (align-corners) -----------------------
__global__ void k_tables(float* __restrict__ ws) {
    int t = threadIdx.x;
    int*   y0i = (int*)(ws + F_Y0I);
    float* wy  = ws + F_WY;
    int*   x0i = (int*)(ws + F_X0I);
    float* wx  = ws + F_WX;
    float* Ry  = ws + F_RY;
    float* Rx  = ws + F_RX;
    for (int idx = t; idx < 4 * 192; idx += 256) {
        int l = idx / 192, Y = idx % 192, h = 48 >> l;
        float step = (float)(h - 1) / 191.0f;
        float ys = step * (float)Y;
        int y0 = (int)floorf(ys);
        y0i[idx] = y0; wy[idx] = ys - (float)y0;
    }
    for (int idx = t; idx < 4 * 640; idx += 256) {
        int l = idx / 640, X = idx % 640, w = 160 >> l;
        float step = (float)(w - 1) / 639.0f;
        float xs = step * (float)X;
        int x0 = (int)floorf(xs);
        x0i[idx] = x0; wx[idx] = xs - (float)x0;
    }
    for (int idx = t; idx < 4 * 48; idx += 256) {
        int l = idx / 48, hh = idx % 48, h = 48 >> l;
        float r = 0.f;
        if (hh < h) {
            float step = (float)(h - 1) / 191.0f;
            for (int Y = 0; Y < 192; ++Y) {
                float ys = step * (float)Y;
                int y0 = (int)floorf(ys);
                float f = ys - (float)y0;
                int y1 = min(y0 + 1, h - 1);
                if (y0 == hh) r += 1.f - f;
                if (y1 == hh) r += f;
            }
        }
        Ry[idx] = r;
    }
    for (int idx = t; idx < 4 * 160; idx += 256) {
        int l = idx / 160, xx = idx % 160, w = 160 >> l;
        float r = 0.f;
        if (xx < w) {
            float step = (float)(w - 1) / 639.0f;
            for (int X = 0; X < 640; ++X) {
                float xs = step * (float)X;
                int x0 = (int)floorf(xs);
                float f = xs - (float)x0;
                int x1 = min(x0 + 1, w - 1);
                if (x0 == xx) r += 1.f - f;
                if (x1 == xx) r += f;
            }
        }
        Rx[idx] = r;
    }
}

// ---------------- Kp: pack lat_w fp32 -> bf16 in fragment-staging order ------
// wp[l][chunk(8)][tap(9)][g(4)][cm(64)][e(8)], ci = chunk*32+g*8+e
__global__ __launch_bounds__(256) void k_pack_w(const float* __restrict__ lat_w,
                                                float* __restrict__ ws) {
    __hip_bfloat16* wp = (__hip_bfloat16*)(ws + F_WPACK);
    int idx = blockIdx.x * 256 + threadIdx.x;
    if (idx >= 589824) return;
    int e = idx & 7; int r = idx >> 3;
    int cm = r & 63; r >>= 6;
    int g = r & 3; r >>= 2;
    int tap = r % 9; r /= 9;
    int chunk = r & 7; int l = r >> 3;
    int ci = chunk * 32 + g * 8 + e;
    float v = lat_w[(((size_t)(l * 64 + cm)) * 256 + ci) * 9 + tap];
    wp[idx] = __float2bfloat16(v);
}

// ---------------- Kc: fpn fp32 NCHW -> bf16 channels-last [b][px][ci] --------
__global__ __launch_bounds__(256) void k_chlast(
    const float* __restrict__ f0, const float* __restrict__ f1,
    const float* __restrict__ f2, const float* __restrict__ f3,
    float* __restrict__ ws)
{
    __shared__ __hip_bfloat16 s[64][264];
    __hip_bfloat16* out = (__hip_bfloat16*)(ws + F_INBF);
    int bid = blockIdx.x;
    int l, base, tpb;
    if (bid < 240)      { l = 0; base = 0;   tpb = 120; }
    else if (bid < 300) { l = 1; base = 240; tpb = 30; }
    else if (bid < 316) { l = 2; base = 300; tpb = 8; }
    else                { l = 3; base = 316; tpb = 2; }
    const float* in = (l == 0) ? f0 : (l == 1) ? f1 : (l == 2) ? f2 : f3;
    const int npx_t[4] = {7680, 1920, 480, 120};
    const size_t ob_t[4] = {0, 3932160, 4915200, 5160960};
    int npx = npx_t[l];
    int local = bid - base;
    int b = local / tpb, ti = local % tpb;
    int px0 = ti * 64;
    int t = threadIdx.x;
    int ciq = t >> 6, pxl = t & 63;
    int px = px0 + pxl;
    bool pv = px < npx;
    const float* ip = in + (size_t)b * 256 * npx + px;
    for (int c4 = 0; c4 < 256; c4 += 4) {
        int ci = c4 + ciq;
        float v = pv ? ip[(size_t)ci * npx] : 0.f;
        s[pxl][ci] = __float2bfloat16(v);
    }
    __syncthreads();
    int pr = t >> 5, seg = t & 31;
    __hip_bfloat16* op = out + ob_t[l] + (size_t)b * npx * 256;
    for (int k = 0; k < 8; ++k) {
        int pxw = px0 + pr + k * 8;
        if (pxw < npx) {
            uint4 v = *(const uint4*)&s[pr + 8 * k][seg * 8];
            *(uint4*)&op[(size_t)pxw * 256 + seg * 8] = v;
        }
    }
}

// ---------------- K1: MFMA conv, all levels, fused finalize+pool -------------
// block = 256 thr = 4 waves; M-tile 128 px (8 rows x 16 cols), N=64 cm, K=2304
__global__ __launch_bounds__(256) void k_conv_mfma(
    float* __restrict__ ws,
    const float* __restrict__ lat_b, const float* __restrict__ lat_s,
    const float* __restrict__ lat_o)
{
    __shared__ __hip_bfloat16 s_a[10][4][18][8];   // 11.5 KB [y][g][x][e]
    __shared__ __hip_bfloat16 s_b[9][4][64][8];    // 36 KB  [tap][g][cm][e]
    const __hip_bfloat16* inbf = (const __hip_bfloat16*)(ws + F_INBF);
    const __hip_bfloat16* wp   = (const __hip_bfloat16*)(ws + F_WPACK);

    int bid = blockIdx.x;
    int l, base, tx_n, ty_n;
    if (bid < 120)      { l = 0; base = 0;   tx_n = 10; ty_n = 6; }
    else if (bid < 150) { l = 1; base = 120; tx_n = 5;  ty_n = 3; }
    else if (bid < 162) { l = 2; base = 150; tx_n = 3;  ty_n = 2; }
    else                { l = 3; base = 162; tx_n = 2;  ty_n = 1; }
    const int h_t[4] = {48, 24, 12, 6}, w_t[4] = {160, 80, 40, 20};
    const size_t ib_t[4] = {0, 3932160, 4915200, 5160960};
    const int co_t[4] = {CONV_OFF0, CONV_OFF1, CONV_OFF2, CONV_OFF3};
    int h = h_t[l], w = w_t[l];
    int local = bid - base, tpb = tx_n * ty_n;
    int b = local / tpb, r = local % tpb;
    int tyi = r / tx_n, txi = r % tx_n;
    int gy0 = tyi * 8, gx0 = txi * 16;

    int t = threadIdx.x;
    int wid = t >> 6, lane = t & 63;
    int xl = lane & 15, g = lane >> 4;

    const __hip_bfloat16* ibase = inbf + ib_t[l] + (size_t)b * h * w * 256;
    const __hip_bfloat16* wbase = wp + (size_t)l * 147456;

    f32x4 acc[2][4];
#pragma unroll
    for (int mi = 0; mi < 2; ++mi)
#pragma unroll
        for (int ni = 0; ni < 4; ++ni) acc[mi][ni] = (f32x4){0.f, 0.f, 0.f, 0.f};

    int ay = t / 18, ax = t % 18;   // t<180: (y,x) staging slot
    for (int chunk = 0; chunk < 8; ++chunk) {
        // stage A: 10x18 px, 32 ci (64B each)
        if (t < 180) {
            int gy = gy0 - 1 + ay, gx = gx0 - 1 + ax;
            if (gy >= 0 && gy < h && gx >= 0 && gx < w) {
                const uint4* src = (const uint4*)(ibase + ((size_t)gy * w + gx) * 256 + chunk * 32);
#pragma unroll
                for (int gg = 0; gg < 4; ++gg) *(uint4*)&s_a[ay][gg][ax][0] = src[gg];
            } else {
                uint4 z = make_uint4(0, 0, 0, 0);
#pragma unroll
                for (int gg = 0; gg < 4; ++gg) *(uint4*)&s_a[ay][gg][ax][0] = z;
            }
        }
        // stage B: flat 36 KB copy
        {
            const uint4* src = (const uint4*)(wbase + (size_t)chunk * 18432);
            uint4* dst = (uint4*)&s_b[0][0][0][0];
#pragma unroll
            for (int k = 0; k < 9; ++k) dst[t + k * 256] = src[t + k * 256];
        }
        __syncthreads();
#pragma unroll
        for (int tap = 0; tap < 9; ++tap) {
            int ky = tap / 3, kx = tap % 3;
            bf16x8 af[2], bfr[4];
#pragma unroll
            for (int mi = 0; mi < 2; ++mi)
                af[mi] = *(const bf16x8*)&s_a[wid * 2 + mi + ky][g][xl + kx][0];
#pragma unroll
            for (int ni = 0; ni < 4; ++ni)
                bfr[ni] = *(const bf16x8*)&s_b[tap][g][ni * 16 + xl][0];
#pragma unroll
            for (int mi = 0; mi < 2; ++mi)
#pragma unroll
                for (int ni = 0; ni < 4; ++ni)
                    acc[mi][ni] = __builtin_amdgcn_mfma_f32_16x16x32_bf16(
                        af[mi], bfr[ni], acc[mi][ni], 0, 0, 0);
        }
        __syncthreads();
    }

    // epilogue: bias/scale/offset/relu, store channels-last fp32, weighted pool
    float bia[4], sca[4], off[4];
#pragma unroll
    for (int ni = 0; ni < 4; ++ni) {
        int cm = ni * 16 + xl;
        bia[ni] = lat_b[l * 64 + cm];
        sca[ni] = lat_s[l * 64 + cm];
        off[ni] = lat_o[l * 64 + cm];
    }
    float wsum[4] = {0.f, 0.f, 0.f, 0.f};
    float* conv = ws + co_t[l];
#pragma unroll
    for (int mi = 0; mi < 2; ++mi) {
        int oy = gy0 + wid * 2 + mi;
        bool yv = oy < h;
        float ry = yv ? ws[F_RY + l * 48 + oy] : 0.f;
#pragma unroll
        for (int j = 0; j < 4; ++j) {
            int ox = gx0 + g * 4 + j;
            bool v = yv && (ox < w);
            float rx = v ? ws[F_RX + l * 160 + ox] : 0.f;
            float rw = ry * rx;
            size_t rowb = (((size_t)b * h + oy) * w + ox) * 64;
#pragma unroll
            for (int ni = 0; ni < 4; ++ni) {
                float val = fmaxf((acc[mi][ni][j] + bia[ni]) * sca[ni] + off[ni], 0.f);
                if (v) {
                    conv[rowb + ni * 16 + xl] = val;
                    wsum[ni] += val * rw;
                }
            }
        }
    }
#pragma unroll
    for (int ni = 0; ni < 4; ++ni) {
        float s = wsum[ni];
        s += __shfl_xor(s, 16);
        s += __shfl_xor(s, 32);
        if (lane < 16) atomicAdd(ws + F_POOLED + b * 256 + l * 64 + ni * 16 + lane, s);
    }
}

// ---------------- K2b: level-attention gates lw -------------------------------
__global__ void k_lw(float* __restrict__ ws,
                     const float* __restrict__ la_w1, const float* __restrict__ la_b1,
                     const float* __restrict__ la_w2, const float* __restrict__ la_b2)
{
    __shared__ float s_hid[2][32];
    int t = threadIdx.x;
    const float invHW = 1.f / (192.f * 640.f);
    if (t < 64) {
        int bb = t >> 5, j = t & 31;
        float acc = la_b1[j];
        const float* P = ws + F_POOLED + bb * 256;
        for (int c = 0; c < 256; ++c) acc += P[c] * invHW * la_w1[j * 256 + c];
        s_hid[bb][j] = fmaxf(acc, 0.f);
    }
    __syncthreads();
    if (t < 8) {
        int bb = t >> 2, l = t & 3;
        float z = la_b2[l];
        for (int j = 0; j < 32; ++j) z += s_hid[bb][j] * la_w2[l * 32 + j];
        ws[F_LWS + bb * 4 + l] = 1.f + sigm(z);
    }
}

// ---------------- K3: project + gather + (256->128) transform ----------------
__global__ __launch_bounds__(256) void k_gather(
    float* __restrict__ ws,
    const float* __restrict__ points, const float* __restrict__ calib,
    const float* __restrict__ imgt_w, const float* __restrict__ imgt_b,
    const float* __restrict__ imgt_s, const float* __restrict__ imgt_o,
    float* __restrict__ dout)
{
    __shared__ float s_g[32][260];
    __shared__ float s_w[32][132];
    __shared__ int s_vi[32], s_ui[32], s_on[32], s_bi[32];
    int t = threadIdx.x;
    int n0 = blockIdx.x * 32;

    if (t < 32) {
        int n = n0 + t;
        int b = n >> 14;
        const float* P = points + (size_t)n * 5;
        float x = P[1], y = P[2], z = P[3], it = P[4];
        const float* C = calib + b * 12;
        float pu = C[0] * x + C[1] * y + C[2] * z + C[3];
        float pv = C[4] * x + C[5] * y + C[6] * z + C[7];
        float pz = C[8] * x + C[9] * y + C[10] * z + C[11];
        float zs = fmaxf(pz, 1e-5f);
        float u = pu / zs, v = pv / zs;
        int on = (u >= 0.f) && (u < 640.f) && (v >= 0.f) && (v < 192.f) && (pz > 1e-5f);
        s_on[t] = on; s_bi[t] = b;
        s_ui[t] = min(max((int)u, 0), 639);
        s_vi[t] = min(max((int)v, 0), 191);
#pragma unroll
        for (int m = 16; m >= 1; m >>= 1) {
            x += __shfl_xor(x, m); y += __shfl_xor(y, m);
            z += __shfl_xor(z, m); it += __shfl_xor(it, m);
        }
        if (t == 0) {
            atomicAdd(ws + F_PTSUM + 0, x);
            atomicAdd(ws + F_PTSUM + 1, y);
            atomicAdd(ws + F_PTSUM + 2, z);
            atomicAdd(ws + F_PTSUM + 3, it);
        }
    }
    __syncthreads();

    {
        int p = t >> 3, sub = t & 7;
        int l = sub >> 1, cmh = (sub & 1) * 32;
        if (!s_on[p]) {
#pragma unroll
            for (int k = 0; k < 32; k += 4)
                *(float4*)&s_g[p][l * 64 + cmh + k] = make_float4(0.f, 0.f, 0.f, 0.f);
        } else {
            int b = s_bi[p], vi = s_vi[p], ui = s_ui[p];
            int h = 48 >> l, w = 160 >> l;
            const int* y0i = (const int*)(ws + F_Y0I);
            const int* x0i = (const int*)(ws + F_X0I);
            int y0 = y0i[l * 192 + vi]; float fy = ws[F_WY + l * 192 + vi];
            int x0 = x0i[l * 640 + ui]; float fx = ws[F_WX + l * 640 + ui];
            int y1 = min(y0 + 1, h - 1), x1 = min(x0 + 1, w - 1);
            int coff = (l == 0) ? CONV_OFF0 : (l == 1) ? CONV_OFF1 : (l == 2) ? CONV_OFF2 : CONV_OFF3;
            const float* base = ws + coff;
            const float* A00 = base + (((size_t)b * h + y0) * w + x0) * 64;
            const float* A01 = base + (((size_t)b * h + y0) * w + x1) * 64;
            const float* A10 = base + (((size_t)b * h + y1) * w + x0) * 64;
            const float* A11 = base + (((size_t)b * h + y1) * w + x1) * 64;
            float w00 = (1.f - fy) * (1.f - fx), w01 = (1.f - fy) * fx;
            float w10 = fy * (1.f - fx), w11 = fy * fx;
            float sc = ws[F_LWS + b * 4 + l];
#pragma unroll
            for (int k = 0; k < 32; k += 4) {
                float4 v00 = *(const float4*)(A00 + cmh + k);
                float4 v01 = *(const float4*)(A01 + cmh + k);
                float4 v10 = *(const float4*)(A10 + cmh + k);
                float4 v11 = *(const float4*)(A11 + cmh + k);
                float4 r;
                r.x = (w00 * v00.x + w01 * v01.x + w10 * v10.x + w11 * v11.x) * sc;
                r.y = (w00 * v00.y + w01 * v01.y + w10 * v10.y + w11 * v11.y) * sc;
                r.z = (w00 * v00.z + w01 * v01.z + w10 * v10.z + w11 * v11.z) * sc;
                r.w = (w00 * v00.w + w01 * v01.w + w10 * v10.w + w11 * v11.w) * sc;
                *(float4*)&s_g[p][l * 64 + cmh + k] = r;
            }
        }
    }
    __syncthreads();

    {
        float s = 0.f;
#pragma unroll 8
        for (int p = 0; p < 32; ++p) s += s_g[p][t];
        atomicAdd(ws + F_GSUM + t, s);
    }

    int og = t & 31, pg = t >> 5;
    int o4 = og * 4, p4 = pg * 4;
    float4 acc[4];
#pragma unroll
    for (int i = 0; i < 4; ++i) acc[i] = make_float4(0.f, 0.f, 0.f, 0.f);

    for (int ch = 0; ch < 8; ++ch) {
        int c0 = ch * 32;
        __syncthreads();
#pragma unroll
        for (int k = 0; k < 16; ++k) {
            int idx = t + k * 256;
            int o = idx >> 5, cl = idx & 31;
            s_w[cl][o] = imgt_w[(size_t)o * 256 + c0 + cl];
        }
        __syncthreads();
#pragma unroll
        for (int cq = 0; cq < 8; ++cq) {
            int c = c0 + cq * 4, cl = cq * 4;
            float4 w0 = *(const float4*)&s_w[cl + 0][o4];
            float4 w1 = *(const float4*)&s_w[cl + 1][o4];
            float4 w2 = *(const float4*)&s_w[cl + 2][o4];
            float4 w3 = *(const float4*)&s_w[cl + 3][o4];
#pragma unroll
            for (int i = 0; i < 4; ++i) {
                float4 gg = *(const float4*)&s_g[p4 + i][c];
                fma4(acc[i], gg.x, w0);
                fma4(acc[i], gg.y, w1);
                fma4(acc[i], gg.z, w2);
                fma4(acc[i], gg.w, w3);
            }
        }
    }
    float4 vb = *(const float4*)(imgt_b + o4);
    float4 vs = *(const float4*)(imgt_s + o4);
    float4 vo = *(const float4*)(imgt_o + o4);
#pragma unroll
    for (int i = 0; i < 4; ++i) {
        int n = n0 + p4 + i;
        float4 r;
        r.x = (acc[i].x + vb.x) * vs.x + vo.x;
        r.y = (acc[i].y + vb.y) * vs.y + vo.y;
        r.z = (acc[i].z + vb.z) * vs.z + vo.z;
        r.w = (acc[i].w + vb.w) * vs.w + vo.w;
        *(float4*)&dout[(size_t)n * 128 + o4] = r;
    }
}

// ---------------- K4: SE gates ------------------------------------------------
__global__ void k_se(float* __restrict__ ws,
                     const float* __restrict__ imgt_w, const float* __restrict__ imgt_b,
                     const float* __restrict__ imgt_s, const float* __restrict__ imgt_o,
                     const float* __restrict__ pts_w, const float* __restrict__ pts_b,
                     const float* __restrict__ pts_s, const float* __restrict__ pts_o,
                     const float* __restrict__ w1p, const float* __restrict__ w2p,
                     const float* __restrict__ w1i, const float* __restrict__ w2i)
{
    __shared__ float s_cross[256];
    __shared__ float s_hp[128], s_hi[128];
    int t = threadIdx.x;  // 128 threads
    const float invN = 1.f / (float)NPTS;
    float a = 0.f;
    for (int c = 0; c < 256; ++c) a += ws[F_GSUM + c] * imgt_w[(size_t)t * 256 + c];
    s_cross[t] = (a * invN + imgt_b[t]) * imgt_s[t] + imgt_o[t];
    float pp = 0.f;
    for (int k = 0; k < 4; ++k) pp += ws[F_PTSUM + k] * invN * pts_w[t * 4 + k];
    s_cross[128 + t] = (pp + pts_b[t]) * pts_s[t] + pts_o[t];
    __syncthreads();
    float h1 = 0.f, h2 = 0.f;
    for (int c = 0; c < 256; ++c) {
        float cv = s_cross[c];
        h1 += cv * w1p[(size_t)t * 256 + c];
        h2 += cv * w1i[(size_t)t * 256 + c];
    }
    s_hp[t] = fmaxf(h1, 0.f); s_hi[t] = fmaxf(h2, 0.f);
    __syncthreads();
    float g1 = 0.f, g2 = 0.f;
    for (int hh = 0; hh < 128; ++hh) {
        g1 += s_hp[hh] * w2p[(size_t)t * 128 + hh];
        g2 += s_hi[hh] * w2i[(size_t)t * 128 + hh];
    }
    ws[F_GATES + t]       = 1.f + sigm(g1);
    ws[F_GATES + 128 + t] = 1.f + sigm(g2);
}

// ---------------- K5: fuse (in-place on d_out) --------------------------------
__global__ __launch_bounds__(256) void k_fuse(
    float* __restrict__ dout, const float* __restrict__ ws,
    const float* __restrict__ points,
    const float* __restrict__ pts_w, const float* __restrict__ pts_b,
    const float* __restrict__ pts_s, const float* __restrict__ pts_o)
{
    int gid = blockIdx.x * 256 + threadIdx.x;
    int n = gid >> 5, oq = (gid & 31) * 4;
    const float* P = points + (size_t)n * 5;
    float x = P[1], y = P[2], z = P[3], it = P[4];
    float4 img = *(float4*)&dout[(size_t)n * 128 + oq];
    float4 g1 = *(const float4*)(ws + F_GATES + oq);
    float4 g2 = *(const float4*)(ws + F_GATES + 128 + oq);
    float r[4], im[4] = {img.x, img.y, img.z, img.w};
    float ga[4] = {g1.x, g1.y, g1.z, g1.w};
    float gb[4] = {g2.x, g2.y, g2.z, g2.w};
#pragma unroll
    for (int j = 0; j < 4; ++j) {
        int o = oq + j;
        float4 wr = *(const float4*)(pts_w + o * 4);
        float pp = x * wr.x + y * wr.y + z * wr.z + it * wr.w;
        pp = (pp + pts_b[o]) * pts_s[o] + pts_o[o];
        r[j] = fmaxf(im[j] * ga[j] + pp * gb[j], 0.f);
    }
    float4 out4 = make_float4(r[0], r[1], r[2], r[3]);
    *(float4*)&dout[(size_t)n * 128 + oq] = out4;
}

// ---------------- launch ------------------------------------------------------
extern "C" void kernel_launch(void* const* d_in, const int* in_sizes, int n_in,
                              void* d_out, int out_size, void* d_ws, size_t ws_size,
                              hipStream_t stream)
{
    const float* fpn0 = (const float*)d_in[0];
    const float* fpn1 = (const float*)d_in[1];
    const float* fpn2 = (const float*)d_in[2];
    const float* fpn3 = (const float*)d_in[3];
    const float* points = (const float*)d_in[4];
    const float* calib  = (const float*)d_in[5];
    const float* lat_w  = (const float*)d_in[6];
    const float* lat_b  = (const float*)d_in[7];
    const float* lat_s  = (const float*)d_in[8];
    const float* lat_o  = (const float*)d_in[9];
    const float* pts_w  = (const float*)d_in[10];
    const float* pts_b  = (const float*)d_in[11];
    const float* pts_s  = (const float*)d_in[12];
    const float* pts_o  = (const float*)d_in[13];
    const float* imgt_w = (const float*)d_in[14];
    const float* imgt_b = (const float*)d_in[15];
    const float* imgt_s = (const float*)d_in[16];
    const float* imgt_o = (const float*)d_in[17];
    const float* la_w1  = (const float*)d_in[18];
    const float* la_b1  = (const float*)d_in[19];
    const float* la_w2  = (const float*)d_in[20];
    const float* la_b2  = (const float*)d_in[21];
    const float* se_pt_w1  = (const float*)d_in[22];
    const float* se_pt_w2  = (const float*)d_in[23];
    const float* se_img_w1 = (const float*)d_in[24];
    const float* se_img_w2 = (const float*)d_in[25];

    float* ws = (float*)d_ws;
    float* dout = (float*)d_out;

    k_zero_small<<<1, 256, 0, stream>>>(ws);
    k_tables<<<1, 256, 0, stream>>>(ws);
    k_pack_w<<<2304, 256, 0, stream>>>(lat_w, ws);
    k_chlast<<<320, 256, 0, stream>>>(fpn0, fpn1, fpn2, fpn3, ws);
    k_conv_mfma<<<166, 256, 0, stream>>>(ws, lat_b, lat_s, lat_o);
    k_lw<<<1, 64, 0, stream>>>(ws, la_w1, la_b1, la_w2, la_b2);
    k_gather<<<NPTS / 32, 256, 0, stream>>>(ws, points, calib, imgt_w, imgt_b,
                                            imgt_s, imgt_o, dout);
    k_se<<<1, 128, 0, stream>>>(ws, imgt_w, imgt_b, imgt_s, imgt_o,
                                pts_w, pts_b, pts_s, pts_o,
                                se_pt_w1, se_pt_w2, se_img_w1, se_img_w2);
    k_fuse<<<NPTS * 32 / 256, 256, 0, stream>>>(dout, ws, points,
                                                pts_w, pts_b, pts_s, pts_o);
}

// Round 4
// 191.786 us; speedup vs baseline: 3.9880x; 1.4945x over previous
//
#include <hip/hip_runtime.h>
#include <hip/hip_bf16.h>
#include <math.h>

#define NPTS   32768

// Workspace float offsets
#define CONV_OFF0 0
#define CONV_OFF1 983040
#define CONV_OFF2 1228800
#define CONV_OFF3 1290240
#define F_Y0I   1305600   // int[4][192]
#define F_WY    1306368   // float[4][192]
#define F_X0I   1307136   // int[4][640]
#define F_WX    1309696   // float[4][640]
#define F_RY    1312256   // float[4][48]
#define F_RX    1312448   // float[4][160]
#define F_POOLED 1313088  // float[2][256]
#define F_LWS   1313600   // float[2][4]  (1+lw)
#define F_ISUM  1313608   // float[128]  (sum over points of img_pre)
#define F_PTSUM 1313864   // float[4]
#define F_GATES 1313868   // float[2][128]
#define F_END   1314124
#define F_INBF  1314176   // bf16 channels-last inputs: 5,222,400 bf16 ele
#define INBF_ELE 5222400
#define F_WPACK (F_INBF + INBF_ELE/2)   // 3,925,376 ; bf16 packed lat weights 589,824 ele
#define F_IMGTBF (F_WPACK + 294912)     // 4,220,288 ; bf16 imgt_w 32,768 ele -> ends 4,236,672 (16.95 MB)

typedef short bf16x8 __attribute__((ext_vector_type(8)));
typedef float f32x4  __attribute__((ext_vector_type(4)));

__device__ __forceinline__ float sigm(float z) { return 1.f / (1.f + expf(-z)); }

// ---------------- K0: zero accumulators + bilinear tables --------------------
__global__ void k_tables(float* __restrict__ ws) {
    int t = threadIdx.x;
    for (int i = t; i < (F_END - F_RY); i += 256) ws[F_RY + i] = 0.f;
    __syncthreads();
    int*   y0i = (int*)(ws + F_Y0I);
    float* wy  = ws + F_WY;
    int*   x0i = (int*)(ws + F_X0I);
    float* wx  = ws + F_WX;
    for (int idx = t; idx < 4 * 192; idx += 256) {
        int l = idx / 192, Y = idx % 192, h = 48 >> l;
        float step = (float)(h - 1) / 191.0f;
        float ys = step * (float)Y;
        int y0 = (int)floorf(ys);
        float f = ys - (float)y0;
        y0i[idx] = y0; wy[idx] = f;
        int y1 = min(y0 + 1, h - 1);
        atomicAdd(ws + F_RY + l * 48 + y0, 1.f - f);
        atomicAdd(ws + F_RY + l * 48 + y1, f);
    }
    for (int idx = t; idx < 4 * 640; idx += 256) {
        int l = idx / 640, X = idx % 640, w = 160 >> l;
        float step = (float)(w - 1) / 639.0f;
        float xs = step * (float)X;
        int x0 = (int)floorf(xs);
        float f = xs - (float)x0;
        x0i[idx] = x0; wx[idx] = f;
        int x1 = min(x0 + 1, w - 1);
        atomicAdd(ws + F_RX + l * 160 + x0, 1.f - f);
        atomicAdd(ws + F_RX + l * 160 + x1, f);
    }
}

// ---------------- Kp: pack lat_w + imgt_w fp32 -> bf16 -----------------------
// wp[l][chunk(8)][tap(9)][g(4)][cm(64)][e(8)], ci = chunk*32+g*8+e
__global__ __launch_bounds__(256) void k_pack_w(const float* __restrict__ lat_w,
                                                const float* __restrict__ imgt_w,
                                                float* __restrict__ ws) {
    int idx = blockIdx.x * 256 + threadIdx.x;
    if (idx < 589824) {
        __hip_bfloat16* wp = (__hip_bfloat16*)(ws + F_WPACK);
        int e = idx & 7; int r = idx >> 3;
        int cm = r & 63; r >>= 6;
        int g = r & 3; r >>= 2;
        int tap = r % 9; r /= 9;
        int chunk = r & 7; int l = r >> 3;
        int ci = chunk * 32 + g * 8 + e;
        float v = lat_w[(((size_t)(l * 64 + cm)) * 256 + ci) * 9 + tap];
        wp[idx] = __float2bfloat16(v);
    } else if (idx < 589824 + 32768) {
        __hip_bfloat16* wb = (__hip_bfloat16*)(ws + F_IMGTBF);
        int i2 = idx - 589824;
        wb[i2] = __float2bfloat16(imgt_w[i2]);
    }
}

// ---------------- Kc: fpn fp32 NCHW -> bf16 channels-last [b][px][ci] --------
__global__ __launch_bounds__(256) void k_chlast(
    const float* __restrict__ f0, const float* __restrict__ f1,
    const float* __restrict__ f2, const float* __restrict__ f3,
    float* __restrict__ ws)
{
    __shared__ __hip_bfloat16 s[64][264];
    __hip_bfloat16* out = (__hip_bfloat16*)(ws + F_INBF);
    int bid = blockIdx.x;
    int l, base, tpb;
    if (bid < 240)      { l = 0; base = 0;   tpb = 120; }
    else if (bid < 300) { l = 1; base = 240; tpb = 30; }
    else if (bid < 316) { l = 2; base = 300; tpb = 8; }
    else                { l = 3; base = 316; tpb = 2; }
    const float* in = (l == 0) ? f0 : (l == 1) ? f1 : (l == 2) ? f2 : f3;
    const int npx_t[4] = {7680, 1920, 480, 120};
    const size_t ob_t[4] = {0, 3932160, 4915200, 5160960};
    int npx = npx_t[l];
    int local = bid - base;
    int b = local / tpb, ti = local % tpb;
    int px0 = ti * 64;
    int t = threadIdx.x;
    int ciq = t >> 6, pxl = t & 63;
    int px = px0 + pxl;
    bool pv = px < npx;
    const float* ip = in + (size_t)b * 256 * npx + px;
    for (int c4 = 0; c4 < 256; c4 += 4) {
        int ci = c4 + ciq;
        float v = pv ? ip[(size_t)ci * npx] : 0.f;
        s[pxl][ci] = __float2bfloat16(v);
    }
    __syncthreads();
    int pr = t >> 5, seg = t & 31;
    __hip_bfloat16* op = out + ob_t[l] + (size_t)b * npx * 256;
    for (int k = 0; k < 8; ++k) {
        int pxw = px0 + pr + k * 8;
        if (pxw < npx) {
            uint4 v = *(const uint4*)&s[pr + 8 * k][seg * 8];
            *(uint4*)&op[(size_t)pxw * 256 + seg * 8] = v;
        }
    }
}

// ---------------- K1: MFMA conv, all levels, fused finalize+pool -------------
__global__ __launch_bounds__(256) void k_conv_mfma(
    float* __restrict__ ws,
    const float* __restrict__ lat_b, const float* __restrict__ lat_s,
    const float* __restrict__ lat_o)
{
    __shared__ __hip_bfloat16 s_a[10][4][18][8];   // [y][g][x][e]
    __shared__ __hip_bfloat16 s_b[9][4][64][8];    // [tap][g][cm][e]
    const __hip_bfloat16* inbf = (const __hip_bfloat16*)(ws + F_INBF);
    const __hip_bfloat16* wp   = (const __hip_bfloat16*)(ws + F_WPACK);

    int bid = blockIdx.x;
    int l, base, tx_n, ty_n;
    if (bid < 120)      { l = 0; base = 0;   tx_n = 10; ty_n = 6; }
    else if (bid < 150) { l = 1; base = 120; tx_n = 5;  ty_n = 3; }
    else if (bid < 162) { l = 2; base = 150; tx_n = 3;  ty_n = 2; }
    else                { l = 3; base = 162; tx_n = 2;  ty_n = 1; }
    const int h_t[4] = {48, 24, 12, 6}, w_t[4] = {160, 80, 40, 20};
    const size_t ib_t[4] = {0, 3932160, 4915200, 5160960};
    const int co_t[4] = {CONV_OFF0, CONV_OFF1, CONV_OFF2, CONV_OFF3};
    int h = h_t[l], w = w_t[l];
    int local = bid - base, tpb = tx_n * ty_n;
    int b = local / tpb, r = local % tpb;
    int tyi = r / tx_n, txi = r % tx_n;
    int gy0 = tyi * 8, gx0 = txi * 16;

    int t = threadIdx.x;
    int wid = t >> 6, lane = t & 63;
    int xl = lane & 15, g = lane >> 4;

    const __hip_bfloat16* ibase = inbf + ib_t[l] + (size_t)b * h * w * 256;
    const __hip_bfloat16* wbase = wp + (size_t)l * 147456;

    f32x4 acc[2][4];
#pragma unroll
    for (int mi = 0; mi < 2; ++mi)
#pragma unroll
        for (int ni = 0; ni < 4; ++ni) acc[mi][ni] = (f32x4){0.f, 0.f, 0.f, 0.f};

    int ay = t / 18, ax = t % 18;
    for (int chunk = 0; chunk < 8; ++chunk) {
        if (t < 180) {
            int gy = gy0 - 1 + ay, gx = gx0 - 1 + ax;
            if (gy >= 0 && gy < h && gx >= 0 && gx < w) {
                const uint4* src = (const uint4*)(ibase + ((size_t)gy * w + gx) * 256 + chunk * 32);
#pragma unroll
                for (int gg = 0; gg < 4; ++gg) *(uint4*)&s_a[ay][gg][ax][0] = src[gg];
            } else {
                uint4 z = make_uint4(0, 0, 0, 0);
#pragma unroll
                for (int gg = 0; gg < 4; ++gg) *(uint4*)&s_a[ay][gg][ax][0] = z;
            }
        }
        {
            const uint4* src = (const uint4*)(wbase + (size_t)chunk * 18432);
            uint4* dst = (uint4*)&s_b[0][0][0][0];
#pragma unroll
            for (int k = 0; k < 9; ++k) dst[t + k * 256] = src[t + k * 256];
        }
        __syncthreads();
#pragma unroll
        for (int tap = 0; tap < 9; ++tap) {
            int ky = tap / 3, kx = tap % 3;
            bf16x8 af[2], bfr[4];
#pragma unroll
            for (int mi = 0; mi < 2; ++mi)
                af[mi] = *(const bf16x8*)&s_a[wid * 2 + mi + ky][g][xl + kx][0];
#pragma unroll
            for (int ni = 0; ni < 4; ++ni)
                bfr[ni] = *(const bf16x8*)&s_b[tap][g][ni * 16 + xl][0];
#pragma unroll
            for (int mi = 0; mi < 2; ++mi)
#pragma unroll
                for (int ni = 0; ni < 4; ++ni)
                    acc[mi][ni] = __builtin_amdgcn_mfma_f32_16x16x32_bf16(
                        af[mi], bfr[ni], acc[mi][ni], 0, 0, 0);
        }
        __syncthreads();
    }

    float bia[4], sca[4], off[4];
#pragma unroll
    for (int ni = 0; ni < 4; ++ni) {
        int cm = ni * 16 + xl;
        bia[ni] = lat_b[l * 64 + cm];
        sca[ni] = lat_s[l * 64 + cm];
        off[ni] = lat_o[l * 64 + cm];
    }
    float wsum[4] = {0.f, 0.f, 0.f, 0.f};
    float* conv = ws + co_t[l];
#pragma unroll
    for (int mi = 0; mi < 2; ++mi) {
        int oy = gy0 + wid * 2 + mi;
        bool yv = oy < h;
        float ry = yv ? ws[F_RY + l * 48 + oy] : 0.f;
#pragma unroll
        for (int j = 0; j < 4; ++j) {
            int ox = gx0 + g * 4 + j;
            bool v = yv && (ox < w);
            float rx = v ? ws[F_RX + l * 160 + ox] : 0.f;
            float rw = ry * rx;
            size_t rowb = (((size_t)b * h + oy) * w + ox) * 64;
#pragma unroll
            for (int ni = 0; ni < 4; ++ni) {
                float val = fmaxf((acc[mi][ni][j] + bia[ni]) * sca[ni] + off[ni], 0.f);
                if (v) {
                    conv[rowb + ni * 16 + xl] = val;
                    wsum[ni] += val * rw;
                }
            }
        }
    }
#pragma unroll
    for (int ni = 0; ni < 4; ++ni) {
        float s = wsum[ni];
        s += __shfl_xor(s, 16);
        s += __shfl_xor(s, 32);
        if (lane < 16) atomicAdd(ws + F_POOLED + b * 256 + l * 64 + ni * 16 + lane, s);
    }
}

// ---------------- K2b: level-attention gates lw -------------------------------
__global__ void k_lw(float* __restrict__ ws,
                     const float* __restrict__ la_w1, const float* __restrict__ la_b1,
                     const float* __restrict__ la_w2, const float* __restrict__ la_b2)
{
    __shared__ float s_hid[2][32];
    int t = threadIdx.x;
    const float invHW = 1.f / (192.f * 640.f);
    if (t < 64) {
        int bb = t >> 5, j = t & 31;
        float acc = la_b1[j];
        const float* P = ws + F_POOLED + bb * 256;
        for (int c = 0; c < 256; ++c) acc += P[c] * invHW * la_w1[j * 256 + c];
        s_hid[bb][j] = fmaxf(acc, 0.f);
    }
    __syncthreads();
    if (t < 8) {
        int bb = t >> 2, l = t & 3;
        float z = la_b2[l];
        for (int j = 0; j < 32; ++j) z += s_hid[bb][j] * la_w2[l * 32 + j];
        ws[F_LWS + bb * 4 + l] = 1.f + sigm(z);
    }
}

// ---------------- Kpt: points column sums ------------------------------------
__global__ __launch_bounds__(256) void k_ptsum(float* __restrict__ ws,
                                               const float* __restrict__ points) {
    __shared__ float s_pt[4][4];
    int t = threadIdx.x, lane = t & 63, wid = t >> 6;
    float sx = 0.f, sy = 0.f, sz = 0.f, si = 0.f;
    int n0 = blockIdx.x * 512;
#pragma unroll
    for (int k = 0; k < 2; ++k) {
        int n = n0 + k * 256 + t;
        const float* P = points + (size_t)n * 5;
        sx += P[1]; sy += P[2]; sz += P[3]; si += P[4];
    }
#pragma unroll
    for (int m = 32; m >= 1; m >>= 1) {
        sx += __shfl_xor(sx, m); sy += __shfl_xor(sy, m);
        sz += __shfl_xor(sz, m); si += __shfl_xor(si, m);
    }
    if (lane == 0) { s_pt[wid][0] = sx; s_pt[wid][1] = sy; s_pt[wid][2] = sz; s_pt[wid][3] = si; }
    __syncthreads();
    if (t < 4) {
        float s = s_pt[0][t] + s_pt[1][t] + s_pt[2][t] + s_pt[3][t];
        atomicAdd(ws + F_PTSUM + t, s);
    }
}

// ---------------- K3: fused project+gather+MFMA GEMM -> img_pre + isum -------
// 512 blocks x 256 thr; 4 waves/block; each wave owns 16 points.
// LDS-free main loop: each lane gathers its own A fragment (8 channels via
// 4 bilinear corners) and loads B fragments directly (L2-resident bf16 imgt_w).
__global__ __launch_bounds__(256) void k_imgemm(
    float* __restrict__ ws, const float* __restrict__ points,
    const float* __restrict__ calib,
    const float* __restrict__ imgt_b, const float* __restrict__ imgt_s,
    const float* __restrict__ imgt_o, float* __restrict__ dout)
{
    __shared__ float s_isum[4][128];
    const ushort* wbf = (const ushort*)(ws + F_IMGTBF);
    int t = threadIdx.x, wid = t >> 6, lane = t & 63, xl = lane & 15, g = lane >> 4;
    int n = blockIdx.x * 64 + wid * 16 + xl;   // this lane's A-row point
    int b = n >> 14;
    const float* P = points + (size_t)n * 5;
    float px = P[1], py = P[2], pz = P[3];
    const float* C = calib + b * 12;
    float pu = C[0] * px + C[1] * py + C[2]  * pz + C[3];
    float pv = C[4] * px + C[5] * py + C[6]  * pz + C[7];
    float pw = C[8] * px + C[9] * py + C[10] * pz + C[11];
    float zs = fmaxf(pw, 1e-5f);
    float u = pu / zs, v = pv / zs;
    bool on = (u >= 0.f) && (u < 640.f) && (v >= 0.f) && (v < 192.f) && (pw > 1e-5f);
    int ui = min(max((int)u, 0), 639);
    int vi = min(max((int)v, 0), 191);

    f32x4 acc[8];
#pragma unroll
    for (int ni = 0; ni < 8; ++ni) acc[ni] = (f32x4){0.f, 0.f, 0.f, 0.f};

    const int co_t[4] = {CONV_OFF0, CONV_OFF1, CONV_OFF2, CONV_OFF3};
    const float *A00 = ws, *A01 = ws, *A10 = ws, *A11 = ws;
    float W00 = 0.f, W01 = 0.f, W10 = 0.f, W11 = 0.f;

    for (int chunk = 0; chunk < 8; ++chunk) {
        int l = chunk >> 1;
        if ((chunk & 1) == 0 && on) {
            int h = 48 >> l, w = 160 >> l;
            float ys = (float)vi * (float)(h - 1) * (1.f / 191.f);
            int y0 = (int)ys; float fy = ys - (float)y0; int y1 = min(y0 + 1, h - 1);
            float xs = (float)ui * (float)(w - 1) * (1.f / 639.f);
            int x0 = (int)xs; float fx = xs - (float)x0; int x1 = min(x0 + 1, w - 1);
            const float* base = ws + co_t[l] + (size_t)b * h * w * 64;
            A00 = base + ((size_t)y0 * w + x0) * 64;
            A01 = base + ((size_t)y0 * w + x1) * 64;
            A10 = base + ((size_t)y1 * w + x0) * 64;
            A11 = base + ((size_t)y1 * w + x1) * 64;
            float sc = ws[F_LWS + b * 4 + l];
            W00 = (1.f - fy) * (1.f - fx) * sc; W01 = (1.f - fy) * fx * sc;
            W10 = fy * (1.f - fx) * sc;         W11 = fy * fx * sc;
        }
        bf16x8 af;
#pragma unroll
        for (int i = 0; i < 8; ++i) af[i] = 0;
        if (on) {
            int cc = (chunk & 1) * 32 + g * 8;
            float4 a0 = *(const float4*)(A00 + cc), a1 = *(const float4*)(A00 + cc + 4);
            float4 b0 = *(const float4*)(A01 + cc), b1 = *(const float4*)(A01 + cc + 4);
            float4 c0 = *(const float4*)(A10 + cc), c1 = *(const float4*)(A10 + cc + 4);
            float4 d0 = *(const float4*)(A11 + cc), d1 = *(const float4*)(A11 + cc + 4);
            float r[8];
            r[0] = W00 * a0.x + W01 * b0.x + W10 * c0.x + W11 * d0.x;
            r[1] = W00 * a0.y + W01 * b0.y + W10 * c0.y + W11 * d0.y;
            r[2] = W00 * a0.z + W01 * b0.z + W10 * c0.z + W11 * d0.z;
            r[3] = W00 * a0.w + W01 * b0.w + W10 * c0.w + W11 * d0.w;
            r[4] = W00 * a1.x + W01 * b1.x + W10 * c1.x + W11 * d1.x;
            r[5] = W00 * a1.y + W01 * b1.y + W10 * c1.y + W11 * d1.y;
            r[6] = W00 * a1.z + W01 * b1.z + W10 * c1.z + W11 * d1.z;
            r[7] = W00 * a1.w + W01 * b1.w + W10 * c1.w + W11 * d1.w;
#pragma unroll
            for (int i = 0; i < 8; ++i) {
                __hip_bfloat16 hb = __float2bfloat16(r[i]);
                af[i] = *reinterpret_cast<short*>(&hb);
            }
        }
#pragma unroll
        for (int ni = 0; ni < 8; ++ni) {
            bf16x8 bfr = *(const bf16x8*)(wbf + (size_t)(ni * 16 + xl) * 256 + chunk * 32 + g * 8);
            acc[ni] = __builtin_amdgcn_mfma_f32_16x16x32_bf16(af, bfr, acc[ni], 0, 0, 0);
        }
    }

    // epilogue: img_pre affine -> dout ; column sums -> isum
    float isump[8];
#pragma unroll
    for (int ni = 0; ni < 8; ++ni) {
        int o = ni * 16 + xl;
        float ib = imgt_b[o], isc = imgt_s[o], io = imgt_o[o];
        float s = 0.f;
#pragma unroll
        for (int j = 0; j < 4; ++j) {
            int np = blockIdx.x * 64 + wid * 16 + g * 4 + j;   // D row m = g*4+j
            float img = (acc[ni][j] + ib) * isc + io;
            dout[(size_t)np * 128 + o] = img;
            s += img;
        }
        s += __shfl_xor(s, 16);
        s += __shfl_xor(s, 32);
        isump[ni] = s;
    }
    if (lane < 16) {
#pragma unroll
        for (int ni = 0; ni < 8; ++ni) s_isum[wid][ni * 16 + xl] = isump[ni];
    }
    __syncthreads();
    if (t < 128) {
        float s = s_isum[0][t] + s_isum[1][t] + s_isum[2][t] + s_isum[3][t];
        atomicAdd(ws + F_ISUM + t, s);
    }
}

// ---------------- K4: SE gates ------------------------------------------------
__global__ void k_se(float* __restrict__ ws,
                     const float* __restrict__ pts_w, const float* __restrict__ pts_b,
                     const float* __restrict__ pts_s, const float* __restrict__ pts_o,
                     const float* __restrict__ w1p, const float* __restrict__ w2p,
                     const float* __restrict__ w1i, const float* __restrict__ w2i)
{
    __shared__ float s_cross[256];
    __shared__ float s_hp[128], s_hi[128];
    int t = threadIdx.x;  // 128 threads
    const float invN = 1.f / (float)NPTS;
    s_cross[t] = ws[F_ISUM + t] * invN;   // img_pool (img_pre already affine)
    float pp = 0.f;
    for (int k = 0; k < 4; ++k) pp += ws[F_PTSUM + k] * invN * pts_w[t * 4 + k];
    s_cross[128 + t] = (pp + pts_b[t]) * pts_s[t] + pts_o[t];
    __syncthreads();
    float h1 = 0.f, h2 = 0.f;
    for (int c = 0; c < 256; ++c) {
        float cv = s_cross[c];
        h1 += cv * w1p[(size_t)t * 256 + c];
        h2 += cv * w1i[(size_t)t * 256 + c];
    }
    s_hp[t] = fmaxf(h1, 0.f); s_hi[t] = fmaxf(h2, 0.f);
    __syncthreads();
    float g1 = 0.f, g2 = 0.f;
    for (int hh = 0; hh < 128; ++hh) {
        g1 += s_hp[hh] * w2p[(size_t)t * 128 + hh];
        g2 += s_hi[hh] * w2i[(size_t)t * 128 + hh];
    }
    ws[F_GATES + t]       = 1.f + sigm(g1);
    ws[F_GATES + 128 + t] = 1.f + sigm(g2);
}

// ---------------- K5: fuse (in-place on d_out) --------------------------------
__global__ __launch_bounds__(256) void k_fuse(
    float* __restrict__ dout, const float* __restrict__ ws,
    const float* __restrict__ points,
    const float* __restrict__ pts_w, const float* __restrict__ pts_b,
    const float* __restrict__ pts_s, const float* __restrict__ pts_o)
{
    int gid = blockIdx.x * 256 + threadIdx.x;
    int n = gid >> 5, oq = (gid & 31) * 4;
    const float* P = points + (size_t)n * 5;
    float x = P[1], y = P[2], z = P[3], it = P[4];
    float4 img = *(float4*)&dout[(size_t)n * 128 + oq];
    float4 g1 = *(const float4*)(ws + F_GATES + oq);
    float4 g2 = *(const float4*)(ws + F_GATES + 128 + oq);
    float r[4], im[4] = {img.x, img.y, img.z, img.w};
    float ga[4] = {g1.x, g1.y, g1.z, g1.w};
    float gb[4] = {g2.x, g2.y, g2.z, g2.w};
#pragma unroll
    for (int j = 0; j < 4; ++j) {
        int o = oq + j;
        float4 wr = *(const float4*)(pts_w + o * 4);
        float pp = x * wr.x + y * wr.y + z * wr.z + it * wr.w;
        pp = (pp + pts_b[o]) * pts_s[o] + pts_o[o];
        r[j] = fmaxf(im[j] * ga[j] + pp * gb[j], 0.f);
    }
    float4 out4 = make_float4(r[0], r[1], r[2], r[3]);
    *(float4*)&dout[(size_t)n * 128 + oq] = out4;
}

// ---------------- launch ------------------------------------------------------
extern "C" void kernel_launch(void* const* d_in, const int* in_sizes, int n_in,
                              void* d_out, int out_size, void* d_ws, size_t ws_size,
                              hipStream_t stream)
{
    const float* fpn0 = (const float*)d_in[0];
    const float* fpn1 = (const float*)d_in[1];
    const float* fpn2 = (const float*)d_in[2];
    const float* fpn3 = (const float*)d_in[3];
    const float* points = (const float*)d_in[4];
    const float* calib  = (const float*)d_in[5];
    const float* lat_w  = (const float*)d_in[6];
    const float* lat_b  = (const float*)d_in[7];
    const float* lat_s  = (const float*)d_in[8];
    const float* lat_o  = (const float*)d_in[9];
    const float* pts_w  = (const float*)d_in[10];
    const float* pts_b  = (const float*)d_in[11];
    const float* pts_s  = (const float*)d_in[12];
    const float* pts_o  = (const float*)d_in[13];
    const float* imgt_w = (const float*)d_in[14];
    const float* imgt_b = (const float*)d_in[15];
    const float* imgt_s = (const float*)d_in[16];
    const float* imgt_o = (const float*)d_in[17];
    const float* la_w1  = (const float*)d_in[18];
    const float* la_b1  = (const float*)d_in[19];
    const float* la_w2  = (const float*)d_in[20];
    const float* la_b2  = (const float*)d_in[21];
    const float* se_pt_w1  = (const float*)d_in[22];
    const float* se_pt_w2  = (const float*)d_in[23];
    const float* se_img_w1 = (const float*)d_in[24];
    const float* se_img_w2 = (const float*)d_in[25];

    float* ws = (float*)d_ws;
    float* dout = (float*)d_out;

    k_tables<<<1, 256, 0, stream>>>(ws);
    k_pack_w<<<2433, 256, 0, stream>>>(lat_w, imgt_w, ws);
    k_chlast<<<320, 256, 0, stream>>>(fpn0, fpn1, fpn2, fpn3, ws);
    k_conv_mfma<<<166, 256, 0, stream>>>(ws, lat_b, lat_s, lat_o);
    k_lw<<<1, 64, 0, stream>>>(ws, la_w1, la_b1, la_w2, la_b2);
    k_ptsum<<<64, 256, 0, stream>>>(ws, points);
    k_imgemm<<<512, 256, 0, stream>>>(ws, points, calib, imgt_b, imgt_s, imgt_o, dout);
    k_se<<<1, 128, 0, stream>>>(ws, pts_w, pts_b, pts_s, pts_o,
                                se_pt_w1, se_pt_w2, se_img_w1, se_img_w2);
    k_fuse<<<NPTS * 32 / 256, 256, 0, stream>>>(dout, ws, points,
                                                pts_w, pts_b, pts_s, pts_o);
}

// Round 5
// 163.366 us; speedup vs baseline: 4.6817x; 1.1740x over previous
//
#include <hip/hip_runtime.h>
#include <hip/hip_bf16.h>
#include <math.h>

#define NPTS   32768

// Workspace float offsets
#define CONV_OFF0 0
#define CONV_OFF1 983040
#define CONV_OFF2 1228800
#define CONV_OFF3 1290240
#define F_RY    1312256   // float[4][48]
#define F_RX    1312448   // float[4][160]
#define F_POOLED 1313088  // float[2][256]
#define F_LWS   1313600   // float[2][4]  (1+lw)
#define F_ISUM  1313608   // float[128]  (sum over points of img_pre)
#define F_PTSUM 1313864   // float[4]
#define F_GATES 1313868   // float[2][128]
#define F_END   1314124
#define F_INBF  1314176   // bf16 channels-last inputs: 5,222,400 bf16 ele
#define INBF_ELE 5222400
#define F_WPACK (F_INBF + INBF_ELE/2)   // 3,925,376 ; bf16 packed lat weights 589,824 ele
#define F_IMGTBF (F_WPACK + 294912)     // 4,220,288 ; bf16 imgt_w 32,768 ele -> ends 4,236,672 (16.95 MB)

typedef short bf16x8 __attribute__((ext_vector_type(8)));
typedef float f32x4  __attribute__((ext_vector_type(4)));

__device__ __forceinline__ float sigm(float z) { return 1.f / (1.f + expf(-z)); }

// ---------------- K0: zero accumulators + resize row/col weight tables -------
// Analytic gather form (NO atomics — R4's scatter-add serialized 59us on
// same-address atomic contention). 4 blocks x 256 thr; one thread per entry.
__global__ __launch_bounds__(256) void k_tables(float* __restrict__ ws) {
    int gid = blockIdx.x * 256 + threadIdx.x;   // 1024 threads
    // zero accumulator region (POOLED, ISUM, PTSUM, ...)
    for (int i = gid; i < (F_END - F_POOLED); i += 1024) ws[F_POOLED + i] = 0.f;
    // Ry[l][hh]: weight of conv-row hh in the 192-row resized mean
    for (int idx = gid; idx < 4 * 48; idx += 1024) {
        int l = idx / 48, hh = idx % 48, h = 48 >> l;
        float r = 0.f;
        if (hh < h) {
            float step = (float)(h - 1) / 191.0f;
            for (int Y = 0; Y < 192; ++Y) {
                float ys = step * (float)Y;
                int y0 = (int)ys;
                float f = ys - (float)y0;
                int y1 = min(y0 + 1, h - 1);
                if (y0 == hh) r += 1.f - f;
                if (y1 == hh) r += f;
            }
        }
        ws[F_RY + idx] = r;
    }
    // Rx[l][xx]
    for (int idx = gid; idx < 4 * 160; idx += 1024) {
        int l = idx / 160, xx = idx % 160, w = 160 >> l;
        float r = 0.f;
        if (xx < w) {
            float step = (float)(w - 1) / 639.0f;
            for (int X = 0; X < 640; ++X) {
                float xs = step * (float)X;
                int x0 = (int)xs;
                float f = xs - (float)x0;
                int x1 = min(x0 + 1, w - 1);
                if (x0 == xx) r += 1.f - f;
                if (x1 == xx) r += f;
            }
        }
        ws[F_RX + idx] = r;
    }
}

// ---------------- Kp: pack lat_w + imgt_w fp32 -> bf16 -----------------------
// wp[l][chunk(8)][tap(9)][g(4)][cm(64)][e(8)], ci = chunk*32+g*8+e
__global__ __launch_bounds__(256) void k_pack_w(const float* __restrict__ lat_w,
                                                const float* __restrict__ imgt_w,
                                                float* __restrict__ ws) {
    int idx = blockIdx.x * 256 + threadIdx.x;
    if (idx < 589824) {
        __hip_bfloat16* wp = (__hip_bfloat16*)(ws + F_WPACK);
        int e = idx & 7; int r = idx >> 3;
        int cm = r & 63; r >>= 6;
        int g = r & 3; r >>= 2;
        int tap = r % 9; r /= 9;
        int chunk = r & 7; int l = r >> 3;
        int ci = chunk * 32 + g * 8 + e;
        float v = lat_w[(((size_t)(l * 64 + cm)) * 256 + ci) * 9 + tap];
        wp[idx] = __float2bfloat16(v);
    } else if (idx < 589824 + 32768) {
        __hip_bfloat16* wb = (__hip_bfloat16*)(ws + F_IMGTBF);
        int i2 = idx - 589824;
        wb[i2] = __float2bfloat16(imgt_w[i2]);
    }
}

// ---------------- Kc: fpn fp32 NCHW -> bf16 channels-last [b][px][ci] --------
__global__ __launch_bounds__(256) void k_chlast(
    const float* __restrict__ f0, const float* __restrict__ f1,
    const float* __restrict__ f2, const float* __restrict__ f3,
    float* __restrict__ ws)
{
    __shared__ __hip_bfloat16 s[64][264];
    __hip_bfloat16* out = (__hip_bfloat16*)(ws + F_INBF);
    int bid = blockIdx.x;
    int l, base, tpb;
    if (bid < 240)      { l = 0; base = 0;   tpb = 120; }
    else if (bid < 300) { l = 1; base = 240; tpb = 30; }
    else if (bid < 316) { l = 2; base = 300; tpb = 8; }
    else                { l = 3; base = 316; tpb = 2; }
    const float* in = (l == 0) ? f0 : (l == 1) ? f1 : (l == 2) ? f2 : f3;
    const int npx_t[4] = {7680, 1920, 480, 120};
    const size_t ob_t[4] = {0, 3932160, 4915200, 5160960};
    int npx = npx_t[l];
    int local = bid - base;
    int b = local / tpb, ti = local % tpb;
    int px0 = ti * 64;
    int t = threadIdx.x;
    int ciq = t >> 6, pxl = t & 63;
    int px = px0 + pxl;
    bool pv = px < npx;
    const float* ip = in + (size_t)b * 256 * npx + px;
    for (int c4 = 0; c4 < 256; c4 += 4) {
        int ci = c4 + ciq;
        float v = pv ? ip[(size_t)ci * npx] : 0.f;
        s[pxl][ci] = __float2bfloat16(v);
    }
    __syncthreads();
    int pr = t >> 5, seg = t & 31;
    __hip_bfloat16* op = out + ob_t[l] + (size_t)b * npx * 256;
    for (int k = 0; k < 8; ++k) {
        int pxw = px0 + pr + k * 8;
        if (pxw < npx) {
            uint4 v = *(const uint4*)&s[pr + 8 * k][seg * 8];
            *(uint4*)&op[(size_t)pxw * 256 + seg * 8] = v;
        }
    }
}

// ---------------- K1: MFMA conv, all levels, fused finalize+pool -------------
__global__ __launch_bounds__(256) void k_conv_mfma(
    float* __restrict__ ws,
    const float* __restrict__ lat_b, const float* __restrict__ lat_s,
    const float* __restrict__ lat_o)
{
    __shared__ __hip_bfloat16 s_a[10][4][18][8];   // [y][g][x][e]
    __shared__ __hip_bfloat16 s_b[9][4][64][8];    // [tap][g][cm][e]
    const __hip_bfloat16* inbf = (const __hip_bfloat16*)(ws + F_INBF);
    const __hip_bfloat16* wp   = (const __hip_bfloat16*)(ws + F_WPACK);

    int bid = blockIdx.x;
    int l, base, tx_n, ty_n;
    if (bid < 120)      { l = 0; base = 0;   tx_n = 10; ty_n = 6; }
    else if (bid < 150) { l = 1; base = 120; tx_n = 5;  ty_n = 3; }
    else if (bid < 162) { l = 2; base = 150; tx_n = 3;  ty_n = 2; }
    else                { l = 3; base = 162; tx_n = 2;  ty_n = 1; }
    const int h_t[4] = {48, 24, 12, 6}, w_t[4] = {160, 80, 40, 20};
    const size_t ib_t[4] = {0, 3932160, 4915200, 5160960};
    const int co_t[4] = {CONV_OFF0, CONV_OFF1, CONV_OFF2, CONV_OFF3};
    int h = h_t[l], w = w_t[l];
    int local = bid - base, tpb = tx_n * ty_n;
    int b = local / tpb, r = local % tpb;
    int tyi = r / tx_n, txi = r % tx_n;
    int gy0 = tyi * 8, gx0 = txi * 16;

    int t = threadIdx.x;
    int wid = t >> 6, lane = t & 63;
    int xl = lane & 15, g = lane >> 4;

    const __hip_bfloat16* ibase = inbf + ib_t[l] + (size_t)b * h * w * 256;
    const __hip_bfloat16* wbase = wp + (size_t)l * 147456;

    f32x4 acc[2][4];
#pragma unroll
    for (int mi = 0; mi < 2; ++mi)
#pragma unroll
        for (int ni = 0; ni < 4; ++ni) acc[mi][ni] = (f32x4){0.f, 0.f, 0.f, 0.f};

    int ay = t / 18, ax = t % 18;
    for (int chunk = 0; chunk < 8; ++chunk) {
        if (t < 180) {
            int gy = gy0 - 1 + ay, gx = gx0 - 1 + ax;
            if (gy >= 0 && gy < h && gx >= 0 && gx < w) {
                const uint4* src = (const uint4*)(ibase + ((size_t)gy * w + gx) * 256 + chunk * 32);
#pragma unroll
                for (int gg = 0; gg < 4; ++gg) *(uint4*)&s_a[ay][gg][ax][0] = src[gg];
            } else {
                uint4 z = make_uint4(0, 0, 0, 0);
#pragma unroll
                for (int gg = 0; gg < 4; ++gg) *(uint4*)&s_a[ay][gg][ax][0] = z;
            }
        }
        {
            const uint4* src = (const uint4*)(wbase + (size_t)chunk * 18432);
            uint4* dst = (uint4*)&s_b[0][0][0][0];
#pragma unroll
            for (int k = 0; k < 9; ++k) dst[t + k * 256] = src[t + k * 256];
        }
        __syncthreads();
#pragma unroll
        for (int tap = 0; tap < 9; ++tap) {
            int ky = tap / 3, kx = tap % 3;
            bf16x8 af[2], bfr[4];
#pragma unroll
            for (int mi = 0; mi < 2; ++mi)
                af[mi] = *(const bf16x8*)&s_a[wid * 2 + mi + ky][g][xl + kx][0];
#pragma unroll
            for (int ni = 0; ni < 4; ++ni)
                bfr[ni] = *(const bf16x8*)&s_b[tap][g][ni * 16 + xl][0];
#pragma unroll
            for (int mi = 0; mi < 2; ++mi)
#pragma unroll
                for (int ni = 0; ni < 4; ++ni)
                    acc[mi][ni] = __builtin_amdgcn_mfma_f32_16x16x32_bf16(
                        af[mi], bfr[ni], acc[mi][ni], 0, 0, 0);
        }
        __syncthreads();
    }

    float bia[4], sca[4], off[4];
#pragma unroll
    for (int ni = 0; ni < 4; ++ni) {
        int cm = ni * 16 + xl;
        bia[ni] = lat_b[l * 64 + cm];
        sca[ni] = lat_s[l * 64 + cm];
        off[ni] = lat_o[l * 64 + cm];
    }
    float wsum[4] = {0.f, 0.f, 0.f, 0.f};
    float* conv = ws + co_t[l];
#pragma unroll
    for (int mi = 0; mi < 2; ++mi) {
        int oy = gy0 + wid * 2 + mi;
        bool yv = oy < h;
        float ry = yv ? ws[F_RY + l * 48 + oy] : 0.f;
#pragma unroll
        for (int j = 0; j < 4; ++j) {
            int ox = gx0 + g * 4 + j;
            bool v = yv && (ox < w);
            float rx = v ? ws[F_RX + l * 160 + ox] : 0.f;
            float rw = ry * rx;
            size_t rowb = (((size_t)b * h + oy) * w + ox) * 64;
#pragma unroll
            for (int ni = 0; ni < 4; ++ni) {
                float val = fmaxf((acc[mi][ni][j] + bia[ni]) * sca[ni] + off[ni], 0.f);
                if (v) {
                    conv[rowb + ni * 16 + xl] = val;
                    wsum[ni] += val * rw;
                }
            }
        }
    }
#pragma unroll
    for (int ni = 0; ni < 4; ++ni) {
        float s = wsum[ni];
        s += __shfl_xor(s, 16);
        s += __shfl_xor(s, 32);
        if (lane < 16) atomicAdd(ws + F_POOLED + b * 256 + l * 64 + ni * 16 + lane, s);
    }
}

// ---------------- K2b: level-attention gates lw -------------------------------
__global__ void k_lw(float* __restrict__ ws,
                     const float* __restrict__ la_w1, const float* __restrict__ la_b1,
                     const float* __restrict__ la_w2, const float* __restrict__ la_b2)
{
    __shared__ float s_hid[2][32];
    int t = threadIdx.x;
    const float invHW = 1.f / (192.f * 640.f);
    if (t < 64) {
        int bb = t >> 5, j = t & 31;
        float acc = la_b1[j];
        const float* P = ws + F_POOLED + bb * 256;
        for (int c = 0; c < 256; ++c) acc += P[c] * invHW * la_w1[j * 256 + c];
        s_hid[bb][j] = fmaxf(acc, 0.f);
    }
    __syncthreads();
    if (t < 8) {
        int bb = t >> 2, l = t & 3;
        float z = la_b2[l];
        for (int j = 0; j < 32; ++j) z += s_hid[bb][j] * la_w2[l * 32 + j];
        ws[F_LWS + bb * 4 + l] = 1.f + sigm(z);
    }
}

// ---------------- Kpt: points column sums ------------------------------------
__global__ __launch_bounds__(256) void k_ptsum(float* __restrict__ ws,
                                               const float* __restrict__ points) {
    __shared__ float s_pt[4][4];
    int t = threadIdx.x, lane = t & 63, wid = t >> 6;
    float sx = 0.f, sy = 0.f, sz = 0.f, si = 0.f;
    int n0 = blockIdx.x * 512;
#pragma unroll
    for (int k = 0; k < 2; ++k) {
        int n = n0 + k * 256 + t;
        const float* P = points + (size_t)n * 5;
        sx += P[1]; sy += P[2]; sz += P[3]; si += P[4];
    }
#pragma unroll
    for (int m = 32; m >= 1; m >>= 1) {
        sx += __shfl_xor(sx, m); sy += __shfl_xor(sy, m);
        sz += __shfl_xor(sz, m); si += __shfl_xor(si, m);
    }
    if (lane == 0) { s_pt[wid][0] = sx; s_pt[wid][1] = sy; s_pt[wid][2] = sz; s_pt[wid][3] = si; }
    __syncthreads();
    if (t < 4) {
        float s = s_pt[0][t] + s_pt[1][t] + s_pt[2][t] + s_pt[3][t];
        atomicAdd(ws + F_PTSUM + t, s);
    }
}

// ---------------- K3: fused project+gather+MFMA GEMM -> img_pre + isum -------
// 512 blocks x 256 thr; 4 waves/block; each wave owns 16 points.
__global__ __launch_bounds__(256) void k_imgemm(
    float* __restrict__ ws, const float* __restrict__ points,
    const float* __restrict__ calib,
    const float* __restrict__ imgt_b, const float* __restrict__ imgt_s,
    const float* __restrict__ imgt_o, float* __restrict__ dout)
{
    __shared__ float s_isum[4][128];
    const ushort* wbf = (const ushort*)(ws + F_IMGTBF);
    int t = threadIdx.x, wid = t >> 6, lane = t & 63, xl = lane & 15, g = lane >> 4;
    int n = blockIdx.x * 64 + wid * 16 + xl;   // this lane's A-row point
    int b = n >> 14;
    const float* P = points + (size_t)n * 5;
    float px = P[1], py = P[2], pz = P[3];
    const float* C = calib + b * 12;
    float pu = C[0] * px + C[1] * py + C[2]  * pz + C[3];
    float pv = C[4] * px + C[5] * py + C[6]  * pz + C[7];
    float pw = C[8] * px + C[9] * py + C[10] * pz + C[11];
    float zs = fmaxf(pw, 1e-5f);
    float u = pu / zs, v = pv / zs;
    bool on = (u >= 0.f) && (u < 640.f) && (v >= 0.f) && (v < 192.f) && (pw > 1e-5f);
    int ui = min(max((int)u, 0), 639);
    int vi = min(max((int)v, 0), 191);

    f32x4 acc[8];
#pragma unroll
    for (int ni = 0; ni < 8; ++ni) acc[ni] = (f32x4){0.f, 0.f, 0.f, 0.f};

    const int co_t[4] = {CONV_OFF0, CONV_OFF1, CONV_OFF2, CONV_OFF3};
    const float *A00 = ws, *A01 = ws, *A10 = ws, *A11 = ws;
    float W00 = 0.f, W01 = 0.f, W10 = 0.f, W11 = 0.f;

    for (int chunk = 0; chunk < 8; ++chunk) {
        int l = chunk >> 1;
        if ((chunk & 1) == 0 && on) {
            int h = 48 >> l, w = 160 >> l;
            float ys = (float)vi * (float)(h - 1) * (1.f / 191.f);
            int y0 = (int)ys; float fy = ys - (float)y0; int y1 = min(y0 + 1, h - 1);
            float xs = (float)ui * (float)(w - 1) * (1.f / 639.f);
            int x0 = (int)xs; float fx = xs - (float)x0; int x1 = min(x0 + 1, w - 1);
            const float* base = ws + co_t[l] + (size_t)b * h * w * 64;
            A00 = base + ((size_t)y0 * w + x0) * 64;
            A01 = base + ((size_t)y0 * w + x1) * 64;
            A10 = base + ((size_t)y1 * w + x0) * 64;
            A11 = base + ((size_t)y1 * w + x1) * 64;
            float sc = ws[F_LWS + b * 4 + l];
            W00 = (1.f - fy) * (1.f - fx) * sc; W01 = (1.f - fy) * fx * sc;
            W10 = fy * (1.f - fx) * sc;         W11 = fy * fx * sc;
        }
        bf16x8 af;
#pragma unroll
        for (int i = 0; i < 8; ++i) af[i] = 0;
        if (on) {
            int cc = (chunk & 1) * 32 + g * 8;
            float4 a0 = *(const float4*)(A00 + cc), a1 = *(const float4*)(A00 + cc + 4);
            float4 b0 = *(const float4*)(A01 + cc), b1 = *(const float4*)(A01 + cc + 4);
            float4 c0 = *(const float4*)(A10 + cc), c1 = *(const float4*)(A10 + cc + 4);
            float4 d0 = *(const float4*)(A11 + cc), d1 = *(const float4*)(A11 + cc + 4);
            float r[8];
            r[0] = W00 * a0.x + W01 * b0.x + W10 * c0.x + W11 * d0.x;
            r[1] = W00 * a0.y + W01 * b0.y + W10 * c0.y + W11 * d0.y;
            r[2] = W00 * a0.z + W01 * b0.z + W10 * c0.z + W11 * d0.z;
            r[3] = W00 * a0.w + W01 * b0.w + W10 * c0.w + W11 * d0.w;
            r[4] = W00 * a1.x + W01 * b1.x + W10 * c1.x + W11 * d1.x;
            r[5] = W00 * a1.y + W01 * b1.y + W10 * c1.y + W11 * d1.y;
            r[6] = W00 * a1.z + W01 * b1.z + W10 * c1.z + W11 * d1.z;
            r[7] = W00 * a1.w + W01 * b1.w + W10 * c1.w + W11 * d1.w;
#pragma unroll
            for (int i = 0; i < 8; ++i) {
                __hip_bfloat16 hb = __float2bfloat16(r[i]);
                af[i] = *reinterpret_cast<short*>(&hb);
            }
        }
#pragma unroll
        for (int ni = 0; ni < 8; ++ni) {
            bf16x8 bfr = *(const bf16x8*)(wbf + (size_t)(ni * 16 + xl) * 256 + chunk * 32 + g * 8);
            acc[ni] = __builtin_amdgcn_mfma_f32_16x16x32_bf16(af, bfr, acc[ni], 0, 0, 0);
        }
    }

    // epilogue: img_pre affine -> dout ; column sums -> isum
    float isump[8];
#pragma unroll
    for (int ni = 0; ni < 8; ++ni) {
        int o = ni * 16 + xl;
        float ib = imgt_b[o], isc = imgt_s[o], io = imgt_o[o];
        float s = 0.f;
#pragma unroll
        for (int j = 0; j < 4; ++j) {
            int np = blockIdx.x * 64 + wid * 16 + g * 4 + j;   // D row m = g*4+j
            float img = (acc[ni][j] + ib) * isc + io;
            dout[(size_t)np * 128 + o] = img;
            s += img;
        }
        s += __shfl_xor(s, 16);
        s += __shfl_xor(s, 32);
        isump[ni] = s;
    }
    if (lane < 16) {
#pragma unroll
        for (int ni = 0; ni < 8; ++ni) s_isum[wid][ni * 16 + xl] = isump[ni];
    }
    __syncthreads();
    if (t < 128) {
        float s = s_isum[0][t] + s_isum[1][t] + s_isum[2][t] + s_isum[3][t];
        atomicAdd(ws + F_ISUM + t, s);
    }
}

// ---------------- K4: SE gates ------------------------------------------------
__global__ void k_se(float* __restrict__ ws,
                     const float* __restrict__ pts_w, const float* __restrict__ pts_b,
                     const float* __restrict__ pts_s, const float* __restrict__ pts_o,
                     const float* __restrict__ w1p, const float* __restrict__ w2p,
                     const float* __restrict__ w1i, const float* __restrict__ w2i)
{
    __shared__ float s_cross[256];
    __shared__ float s_hp[128], s_hi[128];
    int t = threadIdx.x;  // 128 threads
    const float invN = 1.f / (float)NPTS;
    s_cross[t] = ws[F_ISUM + t] * invN;   // img_pool (img_pre already affine)
    float pp = 0.f;
    for (int k = 0; k < 4; ++k) pp += ws[F_PTSUM + k] * invN * pts_w[t * 4 + k];
    s_cross[128 + t] = (pp + pts_b[t]) * pts_s[t] + pts_o[t];
    __syncthreads();
    float h1 = 0.f, h2 = 0.f;
    for (int c = 0; c < 256; ++c) {
        float cv = s_cross[c];
        h1 += cv * w1p[(size_t)t * 256 + c];
        h2 += cv * w1i[(size_t)t * 256 + c];
    }
    s_hp[t] = fmaxf(h1, 0.f); s_hi[t] = fmaxf(h2, 0.f);
    __syncthreads();
    float g1 = 0.f, g2 = 0.f;
    for (int hh = 0; hh < 128; ++hh) {
        g1 += s_hp[hh] * w2p[(size_t)t * 128 + hh];
        g2 += s_hi[hh] * w2i[(size_t)t * 128 + hh];
    }
    ws[F_GATES + t]       = 1.f + sigm(g1);
    ws[F_GATES + 128 + t] = 1.f + sigm(g2);
}

// ---------------- K5: fuse (in-place on d_out) --------------------------------
__global__ __launch_bounds__(256) void k_fuse(
    float* __restrict__ dout, const float* __restrict__ ws,
    const float* __restrict__ points,
    const float* __restrict__ pts_w, const float* __restrict__ pts_b,
    const float* __restrict__ pts_s, const float* __restrict__ pts_o)
{
    int gid = blockIdx.x * 256 + threadIdx.x;
    int n = gid >> 5, oq = (gid & 31) * 4;
    const float* P = points + (size_t)n * 5;
    float x = P[1], y = P[2], z = P[3], it = P[4];
    float4 img = *(float4*)&dout[(size_t)n * 128 + oq];
    float4 g1 = *(const float4*)(ws + F_GATES + oq);
    float4 g2 = *(const float4*)(ws + F_GATES + 128 + oq);
    float r[4], im[4] = {img.x, img.y, img.z, img.w};
    float ga[4] = {g1.x, g1.y, g1.z, g1.w};
    float gb[4] = {g2.x, g2.y, g2.z, g2.w};
#pragma unroll
    for (int j = 0; j < 4; ++j) {
        int o = oq + j;
        float4 wr = *(const float4*)(pts_w + o * 4);
        float pp = x * wr.x + y * wr.y + z * wr.z + it * wr.w;
        pp = (pp + pts_b[o]) * pts_s[o] + pts_o[o];
        r[j] = fmaxf(im[j] * ga[j] + pp * gb[j], 0.f);
    }
    float4 out4 = make_float4(r[0], r[1], r[2], r[3]);
    *(float4*)&dout[(size_t)n * 128 + oq] = out4;
}

// ---------------- launch ------------------------------------------------------
extern "C" void kernel_launch(void* const* d_in, const int* in_sizes, int n_in,
                              void* d_out, int out_size, void* d_ws, size_t ws_size,
                              hipStream_t stream)
{
    const float* fpn0 = (const float*)d_in[0];
    const float* fpn1 = (const float*)d_in[1];
    const float* fpn2 = (const float*)d_in[2];
    const float* fpn3 = (const float*)d_in[3];
    const float* points = (const float*)d_in[4];
    const float* calib  = (const float*)d_in[5];
    const float* lat_w  = (const float*)d_in[6];
    const float* lat_b  = (const float*)d_in[7];
    const float* lat_s  = (const float*)d_in[8];
    const float* lat_o  = (const float*)d_in[9];
    const float* pts_w  = (const float*)d_in[10];
    const float* pts_b  = (const float*)d_in[11];
    const float* pts_s  = (const float*)d_in[12];
    const float* pts_o  = (const float*)d_in[13];
    const float* imgt_w = (const float*)d_in[14];
    const float* imgt_b = (const float*)d_in[15];
    const float* imgt_s = (const float*)d_in[16];
    const float* imgt_o = (const float*)d_in[17];
    const float* la_w1  = (const float*)d_in[18];
    const float* la_b1  = (const float*)d_in[19];
    const float* la_w2  = (const float*)d_in[20];
    const float* la_b2  = (const float*)d_in[21];
    const float* se_pt_w1  = (const float*)d_in[22];
    const float* se_pt_w2  = (const float*)d_in[23];
    const float* se_img_w1 = (const float*)d_in[24];
    const float* se_img_w2 = (const float*)d_in[25];

    float* ws = (float*)d_ws;
    float* dout = (float*)d_out;

    k_tables<<<4, 256, 0, stream>>>(ws);
    k_pack_w<<<2433, 256, 0, stream>>>(lat_w, imgt_w, ws);
    k_chlast<<<320, 256, 0, stream>>>(fpn0, fpn1, fpn2, fpn3, ws);
    k_conv_mfma<<<166, 256, 0, stream>>>(ws, lat_b, lat_s, lat_o);
    k_lw<<<1, 64, 0, stream>>>(ws, la_w1, la_b1, la_w2, la_b2);
    k_ptsum<<<64, 256, 0, stream>>>(ws, points);
    k_imgemm<<<512, 256, 0, stream>>>(ws, points, calib, imgt_b, imgt_s, imgt_o, dout);
    k_se<<<1, 128, 0, stream>>>(ws, pts_w, pts_b, pts_s, pts_o,
                                se_pt_w1, se_pt_w2, se_img_w1, se_img_w2);
    k_fuse<<<NPTS * 32 / 256, 256, 0, stream>>>(dout, ws, points,
                                                pts_w, pts_b, pts_s, pts_o);
}